// Round 4
// baseline (478.841 us; speedup 1.0000x reference)
//
#include <hip/hip_runtime.h>

// ---------------------------------------------------------------------------
// Attention_17703855194398: AdaRMSNorm -> QKV -> per-head RMS+RoPE -> SDPA -> out
// B=2, L=2048, D=2048, NH=32, HD=64, DC=2048
// R7: attn occupancy fix — 32 q/wave (was 64), 128 q/block, grid 1024,
//     4 blocks/CU -> 16 waves/CU (was 8). R4's plain two-barrier staging
//     restored (R5/R6 post-mortem: prefetch restructures lose to implicit
//     cross-block overlap). No setprio, no reg-prefetch.
// ---------------------------------------------------------------------------

typedef __bf16 bf16x8 __attribute__((ext_vector_type(8)));
typedef float  f32x4  __attribute__((ext_vector_type(4)));
typedef float  f32x16 __attribute__((ext_vector_type(16)));

#define EPS_F32 1.1920929e-07f
// q prescale: (1/sqrt(64)) * log2(e)  -> scores land in exp2 domain
#define QSCALE 0.18033688011112042f

#if defined(__has_builtin)
#  if __has_builtin(__builtin_amdgcn_exp2f)
#    define EXP2F(x) __builtin_amdgcn_exp2f(x)
#  else
#    define EXP2F(x) __expf((x) * 0.6931471805599453f)
#  endif
#  if __has_builtin(__builtin_amdgcn_rcpf)
#    define RCPF(x) __builtin_amdgcn_rcpf(x)
#  else
#    define RCPF(x) (1.0f / (x))
#  endif
#else
#  define EXP2F(x) __expf((x) * 0.6931471805599453f)
#  define RCPF(x) (1.0f / (x))
#endif

__device__ __forceinline__ float bf2f(unsigned int u16) {
  union { unsigned int i; float f; } v; v.i = (u16 & 0xffffu) << 16; return v.f;
}
__device__ __forceinline__ unsigned short f2bf(float f) {
  union { float f; unsigned int i; } v; v.f = f;
  unsigned int r = v.i + 0x7fffu + ((v.i >> 16) & 1u);  // RNE
  return (unsigned short)(r >> 16);
}
// round-to-nearest (ties away) bf16 bits, cheap: 2 ops
__device__ __forceinline__ unsigned int f2bf_rn_u(float f) {
  union { float f; unsigned int i; } v; v.f = f;
  return v.i + 0x8000u;   // caller takes >>16 or &0xffff0000
}

// async global->LDS, 16B per lane (wave-uniform base + lane*16)
__device__ __forceinline__ void gload16(const void* g, void* l) {
  __builtin_amdgcn_global_load_lds(
      (const __attribute__((address_space(1))) unsigned int*)(unsigned long long)g,
      (__attribute__((address_space(3))) unsigned int*)(unsigned int)(unsigned long long)l,
      16, 0, 0);
}

// ---------------------------------------------------------------------------
// 1) ada GEMM: ss[b,j] = sum_k cond[b,k] * w_ada[j,k]
// ---------------------------------------------------------------------------
__global__ __launch_bounds__(256) void ada_gemm_kernel(
    const float* __restrict__ cond, const float* __restrict__ w_ada,
    float* __restrict__ ss)
{
  const int lane = threadIdx.x & 63;
  const int gw = blockIdx.x * 4 + (threadIdx.x >> 6);
  const int b = gw >> 12;
  const int j = gw & 4095;
  const float4* wr = (const float4*)(w_ada + j * 2048);
  const float4* cr = (const float4*)(cond + b * 2048);
  float acc = 0.f;
  #pragma unroll
  for (int k4 = 0; k4 < 8; ++k4) {
    float4 w = wr[lane + k4 * 64];
    float4 c = cr[lane + k4 * 64];
    acc += w.x * c.x + w.y * c.y + w.z * c.z + w.w * c.w;
  }
  #pragma unroll
  for (int off = 1; off < 64; off <<= 1) acc += __shfl_xor(acc, off);
  if (lane == 0) ss[b * 4096 + j] = acc;
}

// ---------------------------------------------------------------------------
// 2) AdaRMSNorm: h = rms_norm(x)*(1+scale) + shift, write bf16
// ---------------------------------------------------------------------------
__global__ __launch_bounds__(256) void ada_rms_kernel(
    const float* __restrict__ x, const float* __restrict__ ss,
    unsigned short* __restrict__ H)
{
  const int row = blockIdx.x;
  const int b = row >> 11;
  const int tid = threadIdx.x;
  const int lane = tid & 63, wave = tid >> 6;
  const float* xr = x + (size_t)row * 2048;
  float4 v0 = ((const float4*)xr)[tid * 2];
  float4 v1 = ((const float4*)xr)[tid * 2 + 1];
  float ssq = v0.x*v0.x + v0.y*v0.y + v0.z*v0.z + v0.w*v0.w
            + v1.x*v1.x + v1.y*v1.y + v1.z*v1.z + v1.w*v1.w;
  #pragma unroll
  for (int off = 1; off < 64; off <<= 1) ssq += __shfl_xor(ssq, off);
  __shared__ float red[4];
  if (lane == 0) red[wave] = ssq;
  __syncthreads();
  const float tot = red[0] + red[1] + red[2] + red[3];
  const float r = rsqrtf(tot * (1.f / 2048.f) + EPS_F32);
  const int c0 = tid * 8;
  const float* sh = ss + b * 4096;
  float xv[8] = {v0.x, v0.y, v0.z, v0.w, v1.x, v1.y, v1.z, v1.w};
  unsigned int pk[4];
  #pragma unroll
  for (int p = 0; p < 4; ++p) {
    const int c = c0 + p * 2;
    float h0 = xv[p*2+0] * r * (1.f + sh[2048 + c])     + sh[c];
    float h1 = xv[p*2+1] * r * (1.f + sh[2048 + c + 1]) + sh[c + 1];
    pk[p] = (unsigned int)f2bf(h0) | ((unsigned int)f2bf(h1) << 16);
  }
  *(uint4*)&H[(size_t)row * 2048 + c0] = make_uint4(pk[0], pk[1], pk[2], pk[3]);
}

// ---------------------------------------------------------------------------
// 3) fp32 -> bf16 weight cast, both weights in one launch.
//    dst is contiguous: [w_qkv bf16 : 12582912][w_out bf16 : 4194304]
// ---------------------------------------------------------------------------
__global__ __launch_bounds__(256) void cast2_kernel(
    const float* __restrict__ a,   // w_qkv, 3145728 float4
    const float* __restrict__ b,   // w_out, 1048576 float4
    unsigned short* __restrict__ dst)
{
  const int i = blockIdx.x * 256 + threadIdx.x;   // 0..4194303
  float4 v = (i < 3145728) ? ((const float4*)a)[i]
                           : ((const float4*)b)[i - 3145728];
  unsigned int p0 = (unsigned int)f2bf(v.x) | ((unsigned int)f2bf(v.y) << 16);
  unsigned int p1 = (unsigned int)f2bf(v.z) | ((unsigned int)f2bf(v.w) << 16);
  *(uint2*)&dst[(size_t)i * 4] = make_uint2(p0, p1);
}

// ---------------------------------------------------------------------------
// 4a) bf16 MFMA GEMM, m97 structure (kept for the out-projection, f32 C).
// ---------------------------------------------------------------------------
template <int MODE>
__global__ __launch_bounds__(256) void gemm_bt_kernel(
    const unsigned short* __restrict__ A,   // [M,K] bf16
    const unsigned short* __restrict__ Bw,  // [N,K] bf16
    void* __restrict__ Cv,                  // [M,N] bf16 or f32
    unsigned short* __restrict__ vt,        // MODE 2 only
    int M, int N, int K)
{
  __shared__ unsigned short As[128 * 32];
  __shared__ unsigned short Bs[128 * 32];
  const int tid  = threadIdx.x;
  const int lane = tid & 63;
  const int wave = tid >> 6;
  const int wm = (wave >> 1) * 64;
  const int wn = (wave & 1) * 64;
  const int bm = blockIdx.y * 128;
  const int bn = blockIdx.x * 128;

  f32x4 acc[4][4] = {};

  const int sm = tid >> 2;
  const int sk = (tid & 3) * 8;
  const unsigned short* Ap  = A  + (size_t)(bm + sm) * K + sk;
  const unsigned short* Ap2 = Ap + (size_t)64 * K;
  const unsigned short* Bp  = Bw + (size_t)(bn + sm) * K + sk;
  const unsigned short* Bp2 = Bp + (size_t)64 * K;
  unsigned short* lA  = &As[tid * 8];
  unsigned short* lA2 = &As[tid * 8 + 2048];
  unsigned short* lB  = &Bs[tid * 8];
  unsigned short* lB2 = &Bs[tid * 8 + 2048];

  const int fr = lane & 15;
  const int fk = (lane >> 4) * 8;

  for (int k0 = 0; k0 < K; k0 += 32) {
    __syncthreads();
    gload16(Ap  + k0, lA);
    gload16(Ap2 + k0, lA2);
    gload16(Bp  + k0, lB);
    gload16(Bp2 + k0, lB2);
    __syncthreads();

    bf16x8 af[4], bfr[4];
    #pragma unroll
    for (int i = 0; i < 4; ++i)
      af[i] = *(const bf16x8*)&As[(wm + i * 16 + fr) * 32 + fk];
    #pragma unroll
    for (int j = 0; j < 4; ++j)
      bfr[j] = *(const bf16x8*)&Bs[(wn + j * 16 + fr) * 32 + fk];
    #pragma unroll
    for (int i = 0; i < 4; ++i)
      #pragma unroll
      for (int j = 0; j < 4; ++j)
        acc[i][j] = __builtin_amdgcn_mfma_f32_16x16x32_bf16(af[i], bfr[j], acc[i][j], 0, 0, 0);
  }

  const int cr = (lane >> 4) * 4;
  const int cc = lane & 15;
  if (MODE == 2 && bn >= 4096) {
    #pragma unroll
    for (int i = 0; i < 4; ++i)
      #pragma unroll
      for (int j = 0; j < 4; ++j)
        #pragma unroll
        for (int r = 0; r < 4; ++r) {
          const int m  = bm + wm + i * 16 + cr + r;
          const int dg = bn + wn + j * 16 + cc - 4096;
          const int l  = m & 2047;
          const size_t dst = ((size_t)((m >> 11) * 32 + (dg >> 6)) * 64 + (dg & 63)) * 2048
                           + (l >> 6) * 64 + (l & 15) * 4 + ((l >> 4) & 3);
          vt[dst] = f2bf(acc[i][j][r]);
        }
  } else {
    #pragma unroll
    for (int i = 0; i < 4; ++i)
      #pragma unroll
      for (int j = 0; j < 4; ++j)
        #pragma unroll
        for (int r = 0; r < 4; ++r) {
          const int row = bm + wm + i * 16 + cr + r;
          const int col = bn + wn + j * 16 + cc;
          if (MODE != 0)
            ((unsigned short*)Cv)[(size_t)row * N + col] = f2bf(acc[i][j][r]);
          else
            ((float*)Cv)[(size_t)row * N + col] = acc[i][j][r];
        }
  }
}

// ---------------------------------------------------------------------------
// 4b) QKV GEMM: 256x256 tile, BK=64, 8-phase schedule (8 waves = 2M x 4N).
//    M=4096, N=6144, K=2048 hardcoded. A=[M,K] bf16, Bw=[N,K] bf16.
//    LDS: [buf][khalf][row][32] for A and B (128 KiB total), k-octet slot
//    XOR-swizzle s = q ^ ((row>>1)&3) applied on the GLOBAL source address
//    (global_load_lds writes linearly) and on the ds_read address.
//    vmcnt(4) at phases 2/4/6/8 only — staging loads stay in flight across
//    barriers (2 half-tiles outstanding cover the next 2 phases' reads).
//    Epilogue: cols < 4096 -> linear bf16 QKV; cols >= 4096 -> Vt scatter.
// ---------------------------------------------------------------------------
__global__ __launch_bounds__(512, 2) void gemm_qkv_8p(
    const unsigned short* __restrict__ A,
    const unsigned short* __restrict__ Bw,
    unsigned short* __restrict__ C,
    unsigned short* __restrict__ vt)
{
  __shared__ unsigned short As[2][2][8192];   // [buf][khalf][256 rows * 32 k]
  __shared__ unsigned short Bs[2][2][8192];

  const int tid  = threadIdx.x;
  const int lane = tid & 63;
  const int wave = tid >> 6;              // 0..7
  const int wrow = (wave >> 2) * 128;     // 0 / 128
  const int wcol = (wave & 3) * 64;       // 0 / 64 / 128 / 192

  // bijective XCD chunk swizzle (384 % 8 == 0); chunks are bx-major so each
  // XCD keeps 3 B-panels (3 MB) hot in its L2 while streaming A via L3.
  const int swz = (blockIdx.x & 7) * 48 + (blockIdx.x >> 3);
  const int bx = swz >> 4;                // 0..23  (N tiles)
  const int by = swz & 15;                // 0..15  (M tiles)
  const int bm = by * 256;
  const int bn = bx * 256;

  // fragment-read lane constants (swizzled slot is lane-constant: for rows
  // r = R0 + fr with R0 % 16 == 0, ((r>>1)&3) == ((fr>>1)&3))
  const int fr = lane & 15;
  const int q_ = lane >> 4;
  const int laneoff = fr * 32 + ((q_ ^ ((fr >> 1) & 3)) << 3);

  // staging lane constants: wave w stages rows [w*32, w*32+32) of each half
  const int rA  = wave * 32 + (lane >> 2);            // j=0 row (j=1: +16)
  const int kk  = (lane & 3) ^ ((lane >> 3) & 3);     // inverse-swizzled k-octet
  const unsigned short* Ag0 = A  + (size_t)(bm + rA) * 2048 + kk * 8;
  const unsigned short* Ag1 = Ag0 + (size_t)16 * 2048;
  const unsigned short* Bg0 = Bw + (size_t)(bn + rA) * 2048 + kk * 8;
  const unsigned short* Bg1 = Bg0 + (size_t)16 * 2048;
  const int ldso = rA * 32 + (lane & 3) * 8;          // linear LDS dest (j=1: +512)

  f32x4 acc[8][4] = {};
  bf16x8 fA[4], fB[4];

#define STAGE_A(SB, SKH, KT) do { \
    gload16(Ag0 + (KT) * 64 + (SKH) * 32, &As[SB][SKH][ldso]); \
    gload16(Ag1 + (KT) * 64 + (SKH) * 32, &As[SB][SKH][ldso + 512]); } while (0)
#define STAGE_B(SB, SKH, KT) do { \
    gload16(Bg0 + (KT) * 64 + (SKH) * 32, &Bs[SB][SKH][ldso]); \
    gload16(Bg1 + (KT) * 64 + (SKH) * 32, &Bs[SB][SKH][ldso + 512]); } while (0)
#define VMW(N) asm volatile("s_waitcnt vmcnt(" #N ")" ::: "memory")
#define LDB(BUF, KH) do { const unsigned short* p_ = &Bs[BUF][KH][wcol * 32 + laneoff]; \
    fB[0] = *(const bf16x8*)&p_[0];    fB[1] = *(const bf16x8*)&p_[512]; \
    fB[2] = *(const bf16x8*)&p_[1024]; fB[3] = *(const bf16x8*)&p_[1536]; } while (0)
#define LDA(BUF, KH, MH) do { const unsigned short* p_ = &As[BUF][KH][(wrow + (MH) * 64) * 32 + laneoff]; \
    fA[0] = *(const bf16x8*)&p_[0];    fA[1] = *(const bf16x8*)&p_[512]; \
    fA[2] = *(const bf16x8*)&p_[1024]; fA[3] = *(const bf16x8*)&p_[1536]; } while (0)
#define MFMA16(MH) do { \
    _Pragma("unroll") \
    for (int f_ = 0; f_ < 4; ++f_) { \
      _Pragma("unroll") \
      for (int n_ = 0; n_ < 4; ++n_) \
        acc[(MH) * 4 + f_][n_] = __builtin_amdgcn_mfma_f32_16x16x32_bf16( \
            fA[f_], fB[n_], acc[(MH) * 4 + f_][n_], 0, 0, 0); \
    } } while (0)
#define PH_MID() do { __builtin_amdgcn_s_barrier(); \
    asm volatile("s_waitcnt lgkmcnt(0)"); \
    __builtin_amdgcn_s_setprio(1); } while (0)
#define PH_END() do { __builtin_amdgcn_s_setprio(0); \
    __builtin_amdgcn_s_barrier(); } while (0)

  // prologue: stage K-tile 0 into buf0 (order Ak0, Bk0, Ak1, Bk1)
  STAGE_A(0, 0, 0); STAGE_B(0, 0, 0); STAGE_A(0, 1, 0); STAGE_B(0, 1, 0);
  VMW(4);                      // Ak0+Bk0 landed; Ak1+Bk1 still in flight
  __builtin_amdgcn_s_barrier();

  for (int it = 0; it < 16; ++it) {
    const int t1 = 2 * it + 1;
    const int t2 = 2 * it + 2;
    const bool pf = (it < 15);

    // ---- K-tile 2it (buf0); stage K-tile 2it+1 -> buf1 ----
    // P1: (k0, m0)
    LDB(0, 0); LDA(0, 0, 0);
    STAGE_A(1, 0, t1);
    PH_MID(); MFMA16(0); PH_END();
    // P2: (k0, m1)
    LDA(0, 0, 1);
    STAGE_B(1, 0, t1);
    VMW(4);                    // retire prev P7/P8 (buf0 Ak1,Bk1) for P3
    PH_MID(); MFMA16(1); PH_END();
    // P3: (k1, m0)
    LDB(0, 1); LDA(0, 1, 0);
    STAGE_A(1, 1, t1);
    PH_MID(); MFMA16(0); PH_END();
    // P4: (k1, m1)
    LDA(0, 1, 1);
    STAGE_B(1, 1, t1);
    VMW(4);                    // retire P1/P2 (buf1 Ak0,Bk0) for P5
    PH_MID(); MFMA16(1); PH_END();

    // ---- K-tile 2it+1 (buf1); stage K-tile 2it+2 -> buf0 ----
    // P5: (k0, m0)
    LDB(1, 0); LDA(1, 0, 0);
    if (pf) STAGE_A(0, 0, t2);
    PH_MID(); MFMA16(0); PH_END();
    // P6: (k0, m1)
    LDA(1, 0, 1);
    if (pf) { STAGE_B(0, 0, t2); VMW(4); }  // retire P3/P4 (buf1 Ak1,Bk1)
    else    { VMW(0); }                     // last iter: drain P3/P4
    PH_MID(); MFMA16(1); PH_END();
    // P7: (k1, m0)
    LDB(1, 1); LDA(1, 1, 0);
    if (pf) STAGE_A(0, 1, t2);
    PH_MID(); MFMA16(0); PH_END();
    // P8: (k1, m1)
    LDA(1, 1, 1);
    if (pf) STAGE_B(0, 1, t2);
    VMW(4);                    // retire P5/P6 (buf0 Ak0,Bk0) for next P1
    PH_MID(); MFMA16(1); PH_END();
  }

#undef STAGE_A
#undef STAGE_B
#undef VMW
#undef LDB
#undef LDA
#undef MFMA16
#undef PH_MID
#undef PH_END

  // epilogue: per-wave 128x64 C block. bn is a multiple of 256 so each block
  // is purely q/k (linear) or purely v (Vt scatter), same formulas as before.
  const int cr = (lane >> 4) * 4;
  const int cc = lane & 15;
  if (bn >= 4096) {
    #pragma unroll
    for (int mf = 0; mf < 8; ++mf)
      #pragma unroll
      for (int nf = 0; nf < 4; ++nf)
        #pragma unroll
        for (int r = 0; r < 4; ++r) {
          const int m  = bm + wrow + mf * 16 + cr + r;
          const int dg = bn + wcol + nf * 16 + cc - 4096;
          const int l  = m & 2047;
          const size_t dst = ((size_t)((m >> 11) * 32 + (dg >> 6)) * 64 + (dg & 63)) * 2048
                           + (l >> 6) * 64 + (l & 15) * 4 + ((l >> 4) & 3);
          vt[dst] = f2bf(acc[mf][nf][r]);
        }
  } else {
    #pragma unroll
    for (int mf = 0; mf < 8; ++mf)
      #pragma unroll
      for (int nf = 0; nf < 4; ++nf)
        #pragma unroll
        for (int r = 0; r < 4; ++r) {
          const int row = bm + wrow + mf * 16 + cr + r;
          const int col = bn + wcol + nf * 16 + cc;
          C[(size_t)row * 6144 + col] = f2bf(acc[mf][nf][r]);
        }
  }
}

// ---------------------------------------------------------------------------
// 5) per-head RMSNorm(qk_w) + RoPE on q,k in place; q scaled by QSCALE.
// ---------------------------------------------------------------------------
__global__ __launch_bounds__(256) void qk_rope_kernel(
    unsigned short* __restrict__ QKV, const float* __restrict__ rope,
    const float* __restrict__ qk_w)
{
  const int lane = threadIdx.x & 63;
  const int gid = blockIdx.x * 4 + (threadIdx.x >> 6);
  const int l = gid & 2047;
  const int h = (gid >> 11) & 31;
  const int b = gid >> 16;
  const int base = (b * 2048 + l) * 6144 + h * 64 + lane;
  const float r0 = rope[l * 64 + lane];
  const float r1 = rope[131072 + l * 64 + lane];
  const float w  = qk_w[lane];
  #pragma unroll
  for (int t = 0; t < 2; ++t) {        // t=0: q, t=1: k
    const int idx = base + 2048 * t;
    const float v = bf2f(QKV[idx]);
    float sq = v * v;
    #pragma unroll
    for (int off = 1; off < 64; off <<= 1) sq += __shfl_xor(sq, off);
    const float vn = v * rsqrtf(sq * (1.f / 64.f) + EPS_F32) * w;
    const float vp = __shfl_xor(vn, 1);
    const float vh = (lane & 1) ? vp : -vp;
    const float scale = (t == 0) ? QSCALE : 1.0f;
    QKV[idx] = f2bf((vn * r0 + vh * r1) * scale);
  }
}

// ---------------------------------------------------------------------------
// 6) MFMA flash attention (no-max softmax). R7: 32q/wave, 128q/block,
//    k-tile 64, grid 1024 (16 q-tiles x 64 bh), 4 blocks/CU -> 16 waves/CU.
//    Plain R4 two-barrier staging (no prefetch, no setprio).
//    S via 16x16x32 (A=Q regs, B=K LDS), P packed w/ permuted key p=c*4+kj,
//    PV via 32x32x16 (A=P LDS, B=Vt LDS, pre-permuted in global).
// ---------------------------------------------------------------------------
__global__ __launch_bounds__(256, 4) void attn_mfma_kernel(
    const unsigned short* __restrict__ QKV,  // [4096][6144] (q,k roped)
    const unsigned short* __restrict__ Vt,   // [64 bh][64 d][2048 k-perm]
    unsigned short* __restrict__ O)          // [4096][2048]
{
  __shared__ unsigned short Ks[64 * 72];
  __shared__ unsigned short Vs[64 * 72];
  __shared__ unsigned short Ps[4 * 32 * 68];
  const int tid  = threadIdx.x;
  const int lane = tid & 63;
  const int wave = tid >> 6;
  const int blk = blockIdx.x;              // 0..1023
  const int bh = blk & 63;                 // blk%8 == bh%8 -> XCD-affine
  const int qt = blk >> 6;                 // 0..15
  const int b = bh >> 5, h = bh & 31;
  const int rowbase = b << 11;
  const int qbase = qt * 128 + wave * 32;  // 32 q rows per wave

  const int m16  = lane & 15;
  const int quad = lane >> 4;
  const int m32  = lane & 31;
  const int hl   = lane >> 5;

  // Q fragments (already scaled by QSCALE in rope kernel): 2 x 16-row tiles
  bf16x8 qf[2][2];
  #pragma unroll
  for (int qi = 0; qi < 2; ++qi)
    #pragma unroll
    for (int ch = 0; ch < 2; ++ch)
      qf[qi][ch] = *(const bf16x8*)&QKV[(size_t)(rowbase + qbase + qi * 16 + m16) * 6144
                                        + h * 64 + ch * 32 + quad * 8];

  const int sr = tid >> 2;            // staging row 0..63
  const int sc = (tid & 3) * 16;      // staging col (shorts)
  const unsigned short* Kg = QKV + (size_t)(rowbase + sr) * 6144 + 2048 + h * 64 + sc;
  const unsigned short* Vg = Vt + (size_t)(bh * 64 + sr) * 2048 + sc;

  f32x16 accO[2] = {};                    // [d-tile 32] for this wave's 32 q
  float part[2][4] = {};                  // per-16-row-tile row sums
  unsigned short* Pw = &Ps[(wave * 32) * 68];

  for (int kt = 0; kt < 32; ++kt) {
    __syncthreads();
    {
      const uint4* kp = (const uint4*)(Kg + (size_t)kt * 64 * 6144);
      const uint4* vp = (const uint4*)(Vg + kt * 64);
      uint4 k0 = kp[0], k1 = kp[1];
      uint4 v0 = vp[0], v1 = vp[1];
      *(uint4*)&Ks[sr * 72 + sc]     = k0;
      *(uint4*)&Ks[sr * 72 + sc + 8] = k1;
      *(uint4*)&Vs[sr * 72 + sc]     = v0;
      *(uint4*)&Vs[sr * 72 + sc + 8] = v1;
    }
    __syncthreads();

    // S (16x16x32) -> exp2 -> pack P (key perm p = c*4 + kj)
    unsigned int pk[2][4][2];
    #pragma unroll
    for (int kj = 0; kj < 4; ++kj) {
      bf16x8 kf0 = *(const bf16x8*)&Ks[(kj * 16 + m16) * 72 + quad * 8];
      bf16x8 kf1 = *(const bf16x8*)&Ks[(kj * 16 + m16) * 72 + 32 + quad * 8];
      #pragma unroll
      for (int qi = 0; qi < 2; ++qi) {
        f32x4 acc = {};
        acc = __builtin_amdgcn_mfma_f32_16x16x32_bf16(qf[qi][0], kf0, acc, 0, 0, 0);
        acc = __builtin_amdgcn_mfma_f32_16x16x32_bf16(qf[qi][1], kf1, acc, 0, 0, 0);
        #pragma unroll
        for (int r = 0; r < 4; ++r) {
          float p = EXP2F(acc[r]);
          part[qi][r] += p;
          unsigned int pb = f2bf_rn_u(p);
          if (kj == 0)      pk[qi][r][0]  = pb >> 16;
          else if (kj == 1) pk[qi][r][0] |= pb & 0xffff0000u;
          else if (kj == 2) pk[qi][r][1]  = pb >> 16;
          else              pk[qi][r][1] |= pb & 0xffff0000u;
        }
      }
    }
    #pragma unroll
    for (int qi = 0; qi < 2; ++qi)
      #pragma unroll
      for (int r = 0; r < 4; ++r)
        *(uint2*)&Pw[(qi * 16 + quad * 4 + r) * 68 + m16 * 4] =
            make_uint2(pk[qi][r][0], pk[qi][r][1]);
    // wave-private P region: RAW covered by lgkmcnt, no barrier

    // PV (32x32x16): accO[dt], vb0/vb1 are the two 32-d tiles
    #pragma unroll
    for (int ch = 0; ch < 4; ++ch) {
      bf16x8 pa  = *(const bf16x8*)&Pw[m32 * 68 + ch * 16 + hl * 8];
      bf16x8 vb0 = *(const bf16x8*)&Vs[m32 * 72 + ch * 16 + hl * 8];
      bf16x8 vb1 = *(const bf16x8*)&Vs[(32 + m32) * 72 + ch * 16 + hl * 8];
      accO[0] = __builtin_amdgcn_mfma_f32_32x32x16_bf16(pa, vb0, accO[0], 0, 0, 0);
      accO[1] = __builtin_amdgcn_mfma_f32_32x32x16_bf16(pa, vb1, accO[1], 0, 0, 0);
    }
  }

  // reduce row sums over the 16 n-lanes
  #pragma unroll
  for (int qi = 0; qi < 2; ++qi)
    #pragma unroll
    for (int r = 0; r < 4; ++r)
      #pragma unroll
      for (int off = 1; off < 16; off <<= 1)
        part[qi][r] += __shfl_xor(part[qi][r], off);

  // epilogue: gather row sum, divide, store (one 32-row q-subtile)
  #pragma unroll
  for (int reg = 0; reg < 16; ++reg) {
    const int r = reg & 3;
    const int s = reg >> 2;
    const int qsrc = ((2 * s + hl) & 3) * 16 + m16;
    const float rs = __shfl(part[reg >> 3][r], qsrc);
    const float inv = RCPF(rs);
    const int rho = r + 8 * s + 4 * hl;      // row in 32x32 C layout
    const size_t base = (size_t)(rowbase + qbase + rho) * 2048 + h * 64;
    O[base + m32]      = f2bf(accO[0][reg] * inv);
    O[base + 32 + m32] = f2bf(accO[1][reg] * inv);
  }
}

// ---------------------------------------------------------------------------
// launch
// ---------------------------------------------------------------------------
extern "C" void kernel_launch(void* const* d_in, const int* in_sizes, int n_in,
                              void* d_out, int out_size, void* d_ws, size_t ws_size,
                              hipStream_t stream) {
  (void)in_sizes; (void)n_in; (void)out_size; (void)ws_size;
  const float* x     = (const float*)d_in[0];
  const float* cond  = (const float*)d_in[1];
  const float* rope  = (const float*)d_in[2];
  const float* w_ada = (const float*)d_in[3];
  const float* w_qkv = (const float*)d_in[4];
  const float* w_out = (const float*)d_in[5];
  const float* qk_w  = (const float*)d_in[6];
  float* out = (float*)d_out;

  char* ws = (char*)d_ws;
  float*          ss   = (float*)ws;                       // 32 KB
  unsigned short* H    = (unsigned short*)(ws + 32768);    // 16 MB, reused as O
  unsigned short* Wq   = H + 8388608;                      // 24 MB
  unsigned short* Wo   = Wq + 12582912;                    // 8 MB  (contiguous after Wq)
  unsigned short* QKV  = Wo + 4194304;                     // 48 MB (q,k used)
  unsigned short* Vt_g = QKV + 25165824;                   // 16 MB

  ada_gemm_kernel<<<2048, 256, 0, stream>>>(cond, w_ada, ss);
  ada_rms_kernel<<<4096, 256, 0, stream>>>(x, ss, H);
  cast2_kernel<<<16384, 256, 0, stream>>>(w_qkv, w_out, Wq);
  // qkv = H @ w_qkv^T ; q,k -> QKV, v -> Vt_g (transposed + k-permuted)
  gemm_qkv_8p<<<384, 512, 0, stream>>>(H, Wq, QKV, Vt_g);
  qk_rope_kernel<<<32768, 256, 0, stream>>>(QKV, rope, qk_w);
  attn_mfma_kernel<<<1024, 256, 0, stream>>>(QKV, Vt_g, H);
  gemm_bt_kernel<0><<<dim3(16, 32), 256, 0, stream>>>(H, Wo, (void*)out, nullptr, 4096, 2048, 2048);
}

// Round 5
// 469.298 us; speedup vs baseline: 1.0203x; 1.0203x over previous
//
#include <hip/hip_runtime.h>

// ---------------------------------------------------------------------------
// Attention_17703855194398: AdaRMSNorm -> QKV -> per-head RMS+RoPE -> SDPA -> out
// B=2, L=2048, D=2048, NH=32, HD=64, DC=2048
// R8: attn reverted to the verified R4 structure (64q/wave, 512 blocks,
//     plain two-barrier staging — R5/R6/R7 all regressed vs it).
//     qk_rope vectorized: bf16x8 per lane, rotation lane-local, 3 shuffles
//     per 8 elements (was 6 per element), float4 table loads.
// ---------------------------------------------------------------------------

typedef __bf16 bf16x8 __attribute__((ext_vector_type(8)));
typedef float  f32x4  __attribute__((ext_vector_type(4)));
typedef float  f32x16 __attribute__((ext_vector_type(16)));

#define EPS_F32 1.1920929e-07f
// q prescale: (1/sqrt(64)) * log2(e)  -> scores land in exp2 domain
#define QSCALE 0.18033688011112042f

#if defined(__has_builtin)
#  if __has_builtin(__builtin_amdgcn_exp2f)
#    define EXP2F(x) __builtin_amdgcn_exp2f(x)
#  else
#    define EXP2F(x) __expf((x) * 0.6931471805599453f)
#  endif
#  if __has_builtin(__builtin_amdgcn_rcpf)
#    define RCPF(x) __builtin_amdgcn_rcpf(x)
#  else
#    define RCPF(x) (1.0f / (x))
#  endif
#else
#  define EXP2F(x) __expf((x) * 0.6931471805599453f)
#  define RCPF(x) (1.0f / (x))
#endif

__device__ __forceinline__ float bf2f(unsigned int u16) {
  union { unsigned int i; float f; } v; v.i = (u16 & 0xffffu) << 16; return v.f;
}
__device__ __forceinline__ float bf2f_hi(unsigned int u32) {
  union { unsigned int i; float f; } v; v.i = u32 & 0xffff0000u; return v.f;
}
__device__ __forceinline__ unsigned short f2bf(float f) {
  union { float f; unsigned int i; } v; v.f = f;
  unsigned int r = v.i + 0x7fffu + ((v.i >> 16) & 1u);  // RNE
  return (unsigned short)(r >> 16);
}
// round-to-nearest (ties away) bf16 bits, cheap: 2 ops
__device__ __forceinline__ unsigned int f2bf_rn_u(float f) {
  union { float f; unsigned int i; } v; v.f = f;
  return v.i + 0x8000u;   // caller takes >>16 or &0xffff0000
}

// async global->LDS, 16B per lane (wave-uniform base + lane*16)
__device__ __forceinline__ void gload16(const void* g, void* l) {
  __builtin_amdgcn_global_load_lds(
      (const __attribute__((address_space(1))) unsigned int*)(unsigned long long)g,
      (__attribute__((address_space(3))) unsigned int*)(unsigned int)(unsigned long long)l,
      16, 0, 0);
}

// ---------------------------------------------------------------------------
// 1) ada GEMM: ss[b,j] = sum_k cond[b,k] * w_ada[j,k]
// ---------------------------------------------------------------------------
__global__ __launch_bounds__(256) void ada_gemm_kernel(
    const float* __restrict__ cond, const float* __restrict__ w_ada,
    float* __restrict__ ss)
{
  const int lane = threadIdx.x & 63;
  const int gw = blockIdx.x * 4 + (threadIdx.x >> 6);
  const int b = gw >> 12;
  const int j = gw & 4095;
  const float4* wr = (const float4*)(w_ada + j * 2048);
  const float4* cr = (const float4*)(cond + b * 2048);
  float acc = 0.f;
  #pragma unroll
  for (int k4 = 0; k4 < 8; ++k4) {
    float4 w = wr[lane + k4 * 64];
    float4 c = cr[lane + k4 * 64];
    acc += w.x * c.x + w.y * c.y + w.z * c.z + w.w * c.w;
  }
  #pragma unroll
  for (int off = 1; off < 64; off <<= 1) acc += __shfl_xor(acc, off);
  if (lane == 0) ss[b * 4096 + j] = acc;
}

// ---------------------------------------------------------------------------
// 2) AdaRMSNorm: h = rms_norm(x)*(1+scale) + shift, write bf16
// ---------------------------------------------------------------------------
__global__ __launch_bounds__(256) void ada_rms_kernel(
    const float* __restrict__ x, const float* __restrict__ ss,
    unsigned short* __restrict__ H)
{
  const int row = blockIdx.x;
  const int b = row >> 11;
  const int tid = threadIdx.x;
  const int lane = tid & 63, wave = tid >> 6;
  const float* xr = x + (size_t)row * 2048;
  float4 v0 = ((const float4*)xr)[tid * 2];
  float4 v1 = ((const float4*)xr)[tid * 2 + 1];
  float ssq = v0.x*v0.x + v0.y*v0.y + v0.z*v0.z + v0.w*v0.w
            + v1.x*v1.x + v1.y*v1.y + v1.z*v1.z + v1.w*v1.w;
  #pragma unroll
  for (int off = 1; off < 64; off <<= 1) ssq += __shfl_xor(ssq, off);
  __shared__ float red[4];
  if (lane == 0) red[wave] = ssq;
  __syncthreads();
  const float tot = red[0] + red[1] + red[2] + red[3];
  const float r = rsqrtf(tot * (1.f / 2048.f) + EPS_F32);
  const int c0 = tid * 8;
  const float* sh = ss + b * 4096;
  float xv[8] = {v0.x, v0.y, v0.z, v0.w, v1.x, v1.y, v1.z, v1.w};
  unsigned int pk[4];
  #pragma unroll
  for (int p = 0; p < 4; ++p) {
    const int c = c0 + p * 2;
    float h0 = xv[p*2+0] * r * (1.f + sh[2048 + c])     + sh[c];
    float h1 = xv[p*2+1] * r * (1.f + sh[2048 + c + 1]) + sh[c + 1];
    pk[p] = (unsigned int)f2bf(h0) | ((unsigned int)f2bf(h1) << 16);
  }
  *(uint4*)&H[(size_t)row * 2048 + c0] = make_uint4(pk[0], pk[1], pk[2], pk[3]);
}

// ---------------------------------------------------------------------------
// 3) fp32 -> bf16 weight cast, both weights in one launch.
//    dst is contiguous: [w_qkv bf16 : 12582912][w_out bf16 : 4194304]
// ---------------------------------------------------------------------------
__global__ __launch_bounds__(256) void cast2_kernel(
    const float* __restrict__ a,   // w_qkv, 3145728 float4
    const float* __restrict__ b,   // w_out, 1048576 float4
    unsigned short* __restrict__ dst)
{
  const int i = blockIdx.x * 256 + threadIdx.x;   // 0..4194303
  float4 v = (i < 3145728) ? ((const float4*)a)[i]
                           : ((const float4*)b)[i - 3145728];
  unsigned int p0 = (unsigned int)f2bf(v.x) | ((unsigned int)f2bf(v.y) << 16);
  unsigned int p1 = (unsigned int)f2bf(v.z) | ((unsigned int)f2bf(v.w) << 16);
  *(uint2*)&dst[(size_t)i * 4] = make_uint2(p0, p1);
}

// ---------------------------------------------------------------------------
// 4a) bf16 MFMA GEMM, m97 structure (kept for the out-projection, f32 C).
// ---------------------------------------------------------------------------
template <int MODE>
__global__ __launch_bounds__(256) void gemm_bt_kernel(
    const unsigned short* __restrict__ A,   // [M,K] bf16
    const unsigned short* __restrict__ Bw,  // [N,K] bf16
    void* __restrict__ Cv,                  // [M,N] bf16 or f32
    unsigned short* __restrict__ vt,        // MODE 2 only
    int M, int N, int K)
{
  __shared__ unsigned short As[128 * 32];
  __shared__ unsigned short Bs[128 * 32];
  const int tid  = threadIdx.x;
  const int lane = tid & 63;
  const int wave = tid >> 6;
  const int wm = (wave >> 1) * 64;
  const int wn = (wave & 1) * 64;
  const int bm = blockIdx.y * 128;
  const int bn = blockIdx.x * 128;

  f32x4 acc[4][4] = {};

  const int sm = tid >> 2;
  const int sk = (tid & 3) * 8;
  const unsigned short* Ap  = A  + (size_t)(bm + sm) * K + sk;
  const unsigned short* Ap2 = Ap + (size_t)64 * K;
  const unsigned short* Bp  = Bw + (size_t)(bn + sm) * K + sk;
  const unsigned short* Bp2 = Bp + (size_t)64 * K;
  unsigned short* lA  = &As[tid * 8];
  unsigned short* lA2 = &As[tid * 8 + 2048];
  unsigned short* lB  = &Bs[tid * 8];
  unsigned short* lB2 = &Bs[tid * 8 + 2048];

  const int fr = lane & 15;
  const int fk = (lane >> 4) * 8;

  for (int k0 = 0; k0 < K; k0 += 32) {
    __syncthreads();
    gload16(Ap  + k0, lA);
    gload16(Ap2 + k0, lA2);
    gload16(Bp  + k0, lB);
    gload16(Bp2 + k0, lB2);
    __syncthreads();

    bf16x8 af[4], bfr[4];
    #pragma unroll
    for (int i = 0; i < 4; ++i)
      af[i] = *(const bf16x8*)&As[(wm + i * 16 + fr) * 32 + fk];
    #pragma unroll
    for (int j = 0; j < 4; ++j)
      bfr[j] = *(const bf16x8*)&Bs[(wn + j * 16 + fr) * 32 + fk];
    #pragma unroll
    for (int i = 0; i < 4; ++i)
      #pragma unroll
      for (int j = 0; j < 4; ++j)
        acc[i][j] = __builtin_amdgcn_mfma_f32_16x16x32_bf16(af[i], bfr[j], acc[i][j], 0, 0, 0);
  }

  const int cr = (lane >> 4) * 4;
  const int cc = lane & 15;
  if (MODE == 2 && bn >= 4096) {
    #pragma unroll
    for (int i = 0; i < 4; ++i)
      #pragma unroll
      for (int j = 0; j < 4; ++j)
        #pragma unroll
        for (int r = 0; r < 4; ++r) {
          const int m  = bm + wm + i * 16 + cr + r;
          const int dg = bn + wn + j * 16 + cc - 4096;
          const int l  = m & 2047;
          const size_t dst = ((size_t)((m >> 11) * 32 + (dg >> 6)) * 64 + (dg & 63)) * 2048
                           + (l >> 6) * 64 + (l & 15) * 4 + ((l >> 4) & 3);
          vt[dst] = f2bf(acc[i][j][r]);
        }
  } else {
    #pragma unroll
    for (int i = 0; i < 4; ++i)
      #pragma unroll
      for (int j = 0; j < 4; ++j)
        #pragma unroll
        for (int r = 0; r < 4; ++r) {
          const int row = bm + wm + i * 16 + cr + r;
          const int col = bn + wn + j * 16 + cc;
          if (MODE != 0)
            ((unsigned short*)Cv)[(size_t)row * N + col] = f2bf(acc[i][j][r]);
          else
            ((float*)Cv)[(size_t)row * N + col] = acc[i][j][r];
        }
  }
}

// ---------------------------------------------------------------------------
// 4b) QKV GEMM: 256x256 tile, BK=64, 8-phase schedule (8 waves = 2M x 4N).
//    M=4096, N=6144, K=2048 hardcoded. A=[M,K] bf16, Bw=[N,K] bf16.
//    LDS: [buf][khalf][row][32] for A and B (128 KiB total), k-octet slot
//    XOR-swizzle s = q ^ ((row>>1)&3) applied on the GLOBAL source address
//    (global_load_lds writes linearly) and on the ds_read address.
//    vmcnt(4) at phases 2/4/6/8 only — staging loads stay in flight across
//    barriers (2 half-tiles outstanding cover the next 2 phases' reads).
//    Epilogue: cols < 4096 -> linear bf16 QKV; cols >= 4096 -> Vt scatter.
// ---------------------------------------------------------------------------
__global__ __launch_bounds__(512, 2) void gemm_qkv_8p(
    const unsigned short* __restrict__ A,
    const unsigned short* __restrict__ Bw,
    unsigned short* __restrict__ C,
    unsigned short* __restrict__ vt)
{
  __shared__ unsigned short As[2][2][8192];   // [buf][khalf][256 rows * 32 k]
  __shared__ unsigned short Bs[2][2][8192];

  const int tid  = threadIdx.x;
  const int lane = tid & 63;
  const int wave = tid >> 6;              // 0..7
  const int wrow = (wave >> 2) * 128;     // 0 / 128
  const int wcol = (wave & 3) * 64;       // 0 / 64 / 128 / 192

  // bijective XCD chunk swizzle (384 % 8 == 0); chunks are bx-major so each
  // XCD keeps 3 B-panels (3 MB) hot in its L2 while streaming A via L3.
  const int swz = (blockIdx.x & 7) * 48 + (blockIdx.x >> 3);
  const int bx = swz >> 4;                // 0..23  (N tiles)
  const int by = swz & 15;                // 0..15  (M tiles)
  const int bm = by * 256;
  const int bn = bx * 256;

  // fragment-read lane constants (swizzled slot is lane-constant: for rows
  // r = R0 + fr with R0 % 16 == 0, ((r>>1)&3) == ((fr>>1)&3))
  const int fr = lane & 15;
  const int q_ = lane >> 4;
  const int laneoff = fr * 32 + ((q_ ^ ((fr >> 1) & 3)) << 3);

  // staging lane constants: wave w stages rows [w*32, w*32+32) of each half
  const int rA  = wave * 32 + (lane >> 2);            // j=0 row (j=1: +16)
  const int kk  = (lane & 3) ^ ((lane >> 3) & 3);     // inverse-swizzled k-octet
  const unsigned short* Ag0 = A  + (size_t)(bm + rA) * 2048 + kk * 8;
  const unsigned short* Ag1 = Ag0 + (size_t)16 * 2048;
  const unsigned short* Bg0 = Bw + (size_t)(bn + rA) * 2048 + kk * 8;
  const unsigned short* Bg1 = Bg0 + (size_t)16 * 2048;
  const int ldso = rA * 32 + (lane & 3) * 8;          // linear LDS dest (j=1: +512)

  f32x4 acc[8][4] = {};
  bf16x8 fA[4], fB[4];

#define STAGE_A(SB, SKH, KT) do { \
    gload16(Ag0 + (KT) * 64 + (SKH) * 32, &As[SB][SKH][ldso]); \
    gload16(Ag1 + (KT) * 64 + (SKH) * 32, &As[SB][SKH][ldso + 512]); } while (0)
#define STAGE_B(SB, SKH, KT) do { \
    gload16(Bg0 + (KT) * 64 + (SKH) * 32, &Bs[SB][SKH][ldso]); \
    gload16(Bg1 + (KT) * 64 + (SKH) * 32, &Bs[SB][SKH][ldso + 512]); } while (0)
#define VMW(N) asm volatile("s_waitcnt vmcnt(" #N ")" ::: "memory")
#define LDB(BUF, KH) do { const unsigned short* p_ = &Bs[BUF][KH][wcol * 32 + laneoff]; \
    fB[0] = *(const bf16x8*)&p_[0];    fB[1] = *(const bf16x8*)&p_[512]; \
    fB[2] = *(const bf16x8*)&p_[1024]; fB[3] = *(const bf16x8*)&p_[1536]; } while (0)
#define LDA(BUF, KH, MH) do { const unsigned short* p_ = &As[BUF][KH][(wrow + (MH) * 64) * 32 + laneoff]; \
    fA[0] = *(const bf16x8*)&p_[0];    fA[1] = *(const bf16x8*)&p_[512]; \
    fA[2] = *(const bf16x8*)&p_[1024]; fA[3] = *(const bf16x8*)&p_[1536]; } while (0)
#define MFMA16(MH) do { \
    _Pragma("unroll") \
    for (int f_ = 0; f_ < 4; ++f_) { \
      _Pragma("unroll") \
      for (int n_ = 0; n_ < 4; ++n_) \
        acc[(MH) * 4 + f_][n_] = __builtin_amdgcn_mfma_f32_16x16x32_bf16( \
            fA[f_], fB[n_], acc[(MH) * 4 + f_][n_], 0, 0, 0); \
    } } while (0)
#define PH_MID() do { __builtin_amdgcn_s_barrier(); \
    asm volatile("s_waitcnt lgkmcnt(0)"); \
    __builtin_amdgcn_s_setprio(1); } while (0)
#define PH_END() do { __builtin_amdgcn_s_setprio(0); \
    __builtin_amdgcn_s_barrier(); } while (0)

  // prologue: stage K-tile 0 into buf0 (order Ak0, Bk0, Ak1, Bk1)
  STAGE_A(0, 0, 0); STAGE_B(0, 0, 0); STAGE_A(0, 1, 0); STAGE_B(0, 1, 0);
  VMW(4);                      // Ak0+Bk0 landed; Ak1+Bk1 still in flight
  __builtin_amdgcn_s_barrier();

  for (int it = 0; it < 16; ++it) {
    const int t1 = 2 * it + 1;
    const int t2 = 2 * it + 2;
    const bool pf = (it < 15);

    // ---- K-tile 2it (buf0); stage K-tile 2it+1 -> buf1 ----
    // P1: (k0, m0)
    LDB(0, 0); LDA(0, 0, 0);
    STAGE_A(1, 0, t1);
    PH_MID(); MFMA16(0); PH_END();
    // P2: (k0, m1)
    LDA(0, 0, 1);
    STAGE_B(1, 0, t1);
    VMW(4);                    // retire prev P7/P8 (buf0 Ak1,Bk1) for P3
    PH_MID(); MFMA16(1); PH_END();
    // P3: (k1, m0)
    LDB(0, 1); LDA(0, 1, 0);
    STAGE_A(1, 1, t1);
    PH_MID(); MFMA16(0); PH_END();
    // P4: (k1, m1)
    LDA(0, 1, 1);
    STAGE_B(1, 1, t1);
    VMW(4);                    // retire P1/P2 (buf1 Ak0,Bk0) for P5
    PH_MID(); MFMA16(1); PH_END();

    // ---- K-tile 2it+1 (buf1); stage K-tile 2it+2 -> buf0 ----
    // P5: (k0, m0)
    LDB(1, 0); LDA(1, 0, 0);
    if (pf) STAGE_A(0, 0, t2);
    PH_MID(); MFMA16(0); PH_END();
    // P6: (k0, m1)
    LDA(1, 0, 1);
    if (pf) { STAGE_B(0, 0, t2); VMW(4); }  // retire P3/P4 (buf1 Ak1,Bk1)
    else    { VMW(0); }                     // last iter: drain P3/P4
    PH_MID(); MFMA16(1); PH_END();
    // P7: (k1, m0)
    LDB(1, 1); LDA(1, 1, 0);
    if (pf) STAGE_A(0, 1, t2);
    PH_MID(); MFMA16(0); PH_END();
    // P8: (k1, m1)
    LDA(1, 1, 1);
    if (pf) STAGE_B(0, 1, t2);
    VMW(4);                    // retire P5/P6 (buf0 Ak0,Bk0) for next P1
    PH_MID(); MFMA16(1); PH_END();
  }

#undef STAGE_A
#undef STAGE_B
#undef VMW
#undef LDB
#undef LDA
#undef MFMA16
#undef PH_MID
#undef PH_END

  // epilogue: per-wave 128x64 C block. bn is a multiple of 256 so each block
  // is purely q/k (linear) or purely v (Vt scatter), same formulas as before.
  const int cr = (lane >> 4) * 4;
  const int cc = lane & 15;
  if (bn >= 4096) {
    #pragma unroll
    for (int mf = 0; mf < 8; ++mf)
      #pragma unroll
      for (int nf = 0; nf < 4; ++nf)
        #pragma unroll
        for (int r = 0; r < 4; ++r) {
          const int m  = bm + wrow + mf * 16 + cr + r;
          const int dg = bn + wcol + nf * 16 + cc - 4096;
          const int l  = m & 2047;
          const size_t dst = ((size_t)((m >> 11) * 32 + (dg >> 6)) * 64 + (dg & 63)) * 2048
                           + (l >> 6) * 64 + (l & 15) * 4 + ((l >> 4) & 3);
          vt[dst] = f2bf(acc[mf][nf][r]);
        }
  } else {
    #pragma unroll
    for (int mf = 0; mf < 8; ++mf)
      #pragma unroll
      for (int nf = 0; nf < 4; ++nf)
        #pragma unroll
        for (int r = 0; r < 4; ++r) {
          const int row = bm + wrow + mf * 16 + cr + r;
          const int col = bn + wcol + nf * 16 + cc;
          C[(size_t)row * 6144 + col] = f2bf(acc[mf][nf][r]);
        }
  }
}

// ---------------------------------------------------------------------------
// 5) per-head RMSNorm(qk_w) + RoPE on q,k in place; q scaled by QSCALE.
//    R8: vectorized — bf16x8 per lane (8 dims), 8 lanes per head-row,
//    8 rows per wave (8 heads of one (b,l)). RoPE pairs are lane-local.
// ---------------------------------------------------------------------------
__global__ __launch_bounds__(256) void qk_rope_kernel(
    unsigned short* __restrict__ QKV, const float* __restrict__ rope,
    const float* __restrict__ qk_w)
{
  const int tid  = threadIdx.x;
  const int lane = tid & 63;
  const int task = blockIdx.x * 4 + (tid >> 6);   // 0..16383 = bl*4 + hg
  const int hg   = task & 3;                      // head group (8 heads)
  const int bl   = task >> 2;                     // b*2048 + l
  const int l    = bl & 2047;
  const int h    = hg * 8 + (lane >> 3);
  const int d0   = (lane & 7) * 8;
  const size_t base = (size_t)bl * 6144 + h * 64 + d0;

  // rope + weight for this lane's 8 dims (f32, coalesced float4 pairs)
  float r0[8], r1[8], wv[8];
  {
    const float4* p0 = (const float4*)(rope + l * 64 + d0);
    const float4* p1 = (const float4*)(rope + 131072 + l * 64 + d0);
    const float4* pw = (const float4*)(qk_w + d0);
    float4 a, b2;
    a = p0[0]; b2 = p0[1];
    r0[0]=a.x; r0[1]=a.y; r0[2]=a.z; r0[3]=a.w; r0[4]=b2.x; r0[5]=b2.y; r0[6]=b2.z; r0[7]=b2.w;
    a = p1[0]; b2 = p1[1];
    r1[0]=a.x; r1[1]=a.y; r1[2]=a.z; r1[3]=a.w; r1[4]=b2.x; r1[5]=b2.y; r1[6]=b2.z; r1[7]=b2.w;
    a = pw[0]; b2 = pw[1];
    wv[0]=a.x; wv[1]=a.y; wv[2]=a.z; wv[3]=a.w; wv[4]=b2.x; wv[5]=b2.y; wv[6]=b2.z; wv[7]=b2.w;
  }

  #pragma unroll
  for (int t = 0; t < 2; ++t) {        // t=0: q, t=1: k
    unsigned short* p = &QKV[base + (size_t)2048 * t];
    const uint4 raw = *(const uint4*)p;
    const unsigned int* u = (const unsigned int*)&raw;
    float v[8];
    #pragma unroll
    for (int j = 0; j < 4; ++j) {
      v[2*j]   = bf2f(u[j]);
      v[2*j+1] = bf2f_hi(u[j]);
    }
    float sq = v[0]*v[0] + v[1]*v[1] + v[2]*v[2] + v[3]*v[3]
             + v[4]*v[4] + v[5]*v[5] + v[6]*v[6] + v[7]*v[7];
    sq += __shfl_xor(sq, 1);
    sq += __shfl_xor(sq, 2);
    sq += __shfl_xor(sq, 4);           // sum over the 8 lanes of this row
    const float rn = rsqrtf(sq * (1.f / 64.f) + EPS_F32)
                   * ((t == 0) ? QSCALE : 1.0f);
    float vn[8];
    #pragma unroll
    for (int j = 0; j < 8; ++j) vn[j] = v[j] * (rn * wv[j]);
    unsigned int pk[4];
    #pragma unroll
    for (int j = 0; j < 4; ++j) {      // pair (2j, 2j+1): x_hat = (-x1, x0)
      const float o0 = vn[2*j]   * r0[2*j]   - vn[2*j+1] * r1[2*j];
      const float o1 = vn[2*j+1] * r0[2*j+1] + vn[2*j]   * r1[2*j+1];
      pk[j] = (unsigned int)f2bf(o0) | ((unsigned int)f2bf(o1) << 16);
    }
    *(uint4*)p = make_uint4(pk[0], pk[1], pk[2], pk[3]);
  }
}

// ---------------------------------------------------------------------------
// 6) MFMA flash attention (no-max softmax). 64q/wave, 256q/block, k-tile 64.
//    (verified R4 structure: plain two-barrier staging, no prefetch/setprio)
// ---------------------------------------------------------------------------
__global__ __launch_bounds__(256, 2) void attn_mfma_kernel(
    const unsigned short* __restrict__ QKV,  // [4096][6144] (q,k roped)
    const unsigned short* __restrict__ Vt,   // [64 bh][64 d][2048 k-perm]
    unsigned short* __restrict__ O)          // [4096][2048]
{
  __shared__ unsigned short Ks[64 * 72];
  __shared__ unsigned short Vs[64 * 72];
  __shared__ unsigned short Ps[4 * 64 * 68];
  const int tid  = threadIdx.x;
  const int lane = tid & 63;
  const int wave = tid >> 6;
  const int blk = blockIdx.x;              // 0..511
  const int bh = blk & 63;                 // blk%8 == bh%8 -> XCD-affine
  const int qt = blk >> 6;                 // 0..7
  const int b = bh >> 5, h = bh & 31;
  const int rowbase = b << 11;
  const int qbase = qt * 256 + wave * 64;  // 64 q rows per wave

  const int m16  = lane & 15;
  const int quad = lane >> 4;
  const int m32  = lane & 31;
  const int hl   = lane >> 5;

  // Q fragments (already scaled by QSCALE in rope kernel): 4 x 16-row tiles
  bf16x8 qf[4][2];
  #pragma unroll
  for (int qi = 0; qi < 4; ++qi)
    #pragma unroll
    for (int ch = 0; ch < 2; ++ch)
      qf[qi][ch] = *(const bf16x8*)&QKV[(size_t)(rowbase + qbase + qi * 16 + m16) * 6144
                                        + h * 64 + ch * 32 + quad * 8];

  const int sr = tid >> 2;            // staging row 0..63
  const int sc = (tid & 3) * 16;      // staging col (shorts)
  const unsigned short* Kg = QKV + (size_t)(rowbase + sr) * 6144 + 2048 + h * 64 + sc;
  const unsigned short* Vg = Vt + (size_t)(bh * 64 + sr) * 2048 + sc;

  f32x16 accO[2][2] = {};                 // [q-subtile 32][d-tile 32]
  float part[4][4] = {};                  // per-16-row-tile row sums
  unsigned short* Pw = &Ps[(wave * 64) * 68];

  for (int kt = 0; kt < 32; ++kt) {
    __syncthreads();
    {
      const uint4* kp = (const uint4*)(Kg + (size_t)kt * 64 * 6144);
      const uint4* vp = (const uint4*)(Vg + kt * 64);
      uint4 k0 = kp[0], k1 = kp[1];
      uint4 v0 = vp[0], v1 = vp[1];
      *(uint4*)&Ks[sr * 72 + sc]     = k0;
      *(uint4*)&Ks[sr * 72 + sc + 8] = k1;
      *(uint4*)&Vs[sr * 72 + sc]     = v0;
      *(uint4*)&Vs[sr * 72 + sc + 8] = v1;
    }
    __syncthreads();

    // S (16x16x32) -> exp2 -> pack P (key perm p = c*4 + kj)
    unsigned int pk[4][4][2];
    #pragma unroll
    for (int kj = 0; kj < 4; ++kj) {
      bf16x8 kf0 = *(const bf16x8*)&Ks[(kj * 16 + m16) * 72 + quad * 8];
      bf16x8 kf1 = *(const bf16x8*)&Ks[(kj * 16 + m16) * 72 + 32 + quad * 8];
      #pragma unroll
      for (int qi = 0; qi < 4; ++qi) {
        f32x4 acc = {};
        acc = __builtin_amdgcn_mfma_f32_16x16x32_bf16(qf[qi][0], kf0, acc, 0, 0, 0);
        acc = __builtin_amdgcn_mfma_f32_16x16x32_bf16(qf[qi][1], kf1, acc, 0, 0, 0);
        #pragma unroll
        for (int r = 0; r < 4; ++r) {
          float p = EXP2F(acc[r]);
          part[qi][r] += p;
          unsigned int pb = f2bf_rn_u(p);
          if (kj == 0)      pk[qi][r][0]  = pb >> 16;
          else if (kj == 1) pk[qi][r][0] |= pb & 0xffff0000u;
          else if (kj == 2) pk[qi][r][1]  = pb >> 16;
          else              pk[qi][r][1] |= pb & 0xffff0000u;
        }
      }
    }
    #pragma unroll
    for (int qi = 0; qi < 4; ++qi)
      #pragma unroll
      for (int r = 0; r < 4; ++r)
        *(uint2*)&Pw[(qi * 16 + quad * 4 + r) * 68 + m16 * 4] =
            make_uint2(pk[qi][r][0], pk[qi][r][1]);
    // wave-private P region: RAW covered by lgkmcnt, no barrier

    // PV (32x32x16): accO[qs][dt], vb reused across qs
    #pragma unroll
    for (int ch = 0; ch < 4; ++ch) {
      bf16x8 pa0 = *(const bf16x8*)&Pw[m32 * 68 + ch * 16 + hl * 8];
      bf16x8 pa1 = *(const bf16x8*)&Pw[(32 + m32) * 68 + ch * 16 + hl * 8];
      bf16x8 vb0 = *(const bf16x8*)&Vs[m32 * 72 + ch * 16 + hl * 8];
      bf16x8 vb1 = *(const bf16x8*)&Vs[(32 + m32) * 72 + ch * 16 + hl * 8];
      accO[0][0] = __builtin_amdgcn_mfma_f32_32x32x16_bf16(pa0, vb0, accO[0][0], 0, 0, 0);
      accO[0][1] = __builtin_amdgcn_mfma_f32_32x32x16_bf16(pa0, vb1, accO[0][1], 0, 0, 0);
      accO[1][0] = __builtin_amdgcn_mfma_f32_32x32x16_bf16(pa1, vb0, accO[1][0], 0, 0, 0);
      accO[1][1] = __builtin_amdgcn_mfma_f32_32x32x16_bf16(pa1, vb1, accO[1][1], 0, 0, 0);
    }
  }

  // reduce row sums over the 16 n-lanes
  #pragma unroll
  for (int qi = 0; qi < 4; ++qi)
    #pragma unroll
    for (int r = 0; r < 4; ++r)
      #pragma unroll
      for (int off = 1; off < 16; off <<= 1)
        part[qi][r] += __shfl_xor(part[qi][r], off);

  // epilogue: per 32-row q-subtile, gather row sum, divide, store
  #pragma unroll
  for (int qs = 0; qs < 2; ++qs) {
    #pragma unroll
    for (int reg = 0; reg < 16; ++reg) {
      const int r = reg & 3;
      const int s = reg >> 2;
      const int qsrc = ((2 * s + hl) & 3) * 16 + m16;
      const float rs = __shfl(part[qs * 2 + (reg >> 3)][r], qsrc);
      const float inv = RCPF(rs);
      const int rho = r + 8 * s + 4 * hl;      // row in 32x32 C layout
      const size_t base = (size_t)(rowbase + qbase + qs * 32 + rho) * 2048 + h * 64;
      O[base + m32]      = f2bf(accO[qs][0][reg] * inv);
      O[base + 32 + m32] = f2bf(accO[qs][1][reg] * inv);
    }
  }
}

// ---------------------------------------------------------------------------
// launch
// ---------------------------------------------------------------------------
extern "C" void kernel_launch(void* const* d_in, const int* in_sizes, int n_in,
                              void* d_out, int out_size, void* d_ws, size_t ws_size,
                              hipStream_t stream) {
  (void)in_sizes; (void)n_in; (void)out_size; (void)ws_size;
  const float* x     = (const float*)d_in[0];
  const float* cond  = (const float*)d_in[1];
  const float* rope  = (const float*)d_in[2];
  const float* w_ada = (const float*)d_in[3];
  const float* w_qkv = (const float*)d_in[4];
  const float* w_out = (const float*)d_in[5];
  const float* qk_w  = (const float*)d_in[6];
  float* out = (float*)d_out;

  char* ws = (char*)d_ws;
  float*          ss   = (float*)ws;                       // 32 KB
  unsigned short* H    = (unsigned short*)(ws + 32768);    // 16 MB, reused as O
  unsigned short* Wq   = H + 8388608;                      // 24 MB
  unsigned short* Wo   = Wq + 12582912;                    // 8 MB  (contiguous after Wq)
  unsigned short* QKV  = Wo + 4194304;                     // 48 MB (q,k used)
  unsigned short* Vt_g = QKV + 25165824;                   // 16 MB

  ada_gemm_kernel<<<2048, 256, 0, stream>>>(cond, w_ada, ss);
  ada_rms_kernel<<<4096, 256, 0, stream>>>(x, ss, H);
  cast2_kernel<<<16384, 256, 0, stream>>>(w_qkv, w_out, Wq);
  // qkv = H @ w_qkv^T ; q,k -> QKV, v -> Vt_g (transposed + k-permuted)
  gemm_qkv_8p<<<384, 512, 0, stream>>>(H, Wq, QKV, Vt_g);
  qk_rope_kernel<<<4096, 256, 0, stream>>>(QKV, rope, qk_w);
  attn_mfma_kernel<<<512, 256, 0, stream>>>(QKV, Vt_g, H);
  gemm_bt_kernel<0><<<dim3(16, 32), 256, 0, stream>>>(H, Wo, (void*)out, nullptr, 4096, 2048, 2048);
}

// Round 8
// 447.614 us; speedup vs baseline: 1.0698x; 1.0484x over previous
//
#include <hip/hip_runtime.h>

// ---------------------------------------------------------------------------
// Attention_17703855194398: AdaRMSNorm -> QKV -> per-head RMS+RoPE -> SDPA -> out
// B=2, L=2048, D=2048, NH=32, HD=64, DC=2048
// R11 (= R9 resubmit x2; rounds 6-7 were container-acquire failures, no data):
//     (a) out-projection: 256x128 4-phase kernel, grid 256 = 1 block/CU.
//     (b) qk_rope fused into the QKV GEMM epilogue (RMS on f32 accumulators).
//     attn untouched (verified R4 structure).
// ---------------------------------------------------------------------------

typedef __bf16 bf16x8 __attribute__((ext_vector_type(8)));
typedef float  f32x4  __attribute__((ext_vector_type(4)));
typedef float  f32x16 __attribute__((ext_vector_type(16)));

#define EPS_F32 1.1920929e-07f
// q prescale: (1/sqrt(64)) * log2(e)  -> scores land in exp2 domain
#define QSCALE 0.18033688011112042f

#if defined(__has_builtin)
#  if __has_builtin(__builtin_amdgcn_exp2f)
#    define EXP2F(x) __builtin_amdgcn_exp2f(x)
#  else
#    define EXP2F(x) __expf((x) * 0.6931471805599453f)
#  endif
#  if __has_builtin(__builtin_amdgcn_rcpf)
#    define RCPF(x) __builtin_amdgcn_rcpf(x)
#  else
#    define RCPF(x) (1.0f / (x))
#  endif
#else
#  define EXP2F(x) __expf((x) * 0.6931471805599453f)
#  define RCPF(x) (1.0f / (x))
#endif

__device__ __forceinline__ float bf2f(unsigned int u16) {
  union { unsigned int i; float f; } v; v.i = (u16 & 0xffffu) << 16; return v.f;
}
__device__ __forceinline__ unsigned short f2bf(float f) {
  union { float f; unsigned int i; } v; v.f = f;
  unsigned int r = v.i + 0x7fffu + ((v.i >> 16) & 1u);  // RNE
  return (unsigned short)(r >> 16);
}
// round-to-nearest (ties away) bf16 bits, cheap: 2 ops
__device__ __forceinline__ unsigned int f2bf_rn_u(float f) {
  union { float f; unsigned int i; } v; v.f = f;
  return v.i + 0x8000u;   // caller takes >>16 or &0xffff0000
}

// async global->LDS, 16B per lane (wave-uniform base + lane*16)
__device__ __forceinline__ void gload16(const void* g, void* l) {
  __builtin_amdgcn_global_load_lds(
      (const __attribute__((address_space(1))) unsigned int*)(unsigned long long)g,
      (__attribute__((address_space(3))) unsigned int*)(unsigned int)(unsigned long long)l,
      16, 0, 0);
}

// ---------------------------------------------------------------------------
// 1) ada GEMM: ss[b,j] = sum_k cond[b,k] * w_ada[j,k]
// ---------------------------------------------------------------------------
__global__ __launch_bounds__(256) void ada_gemm_kernel(
    const float* __restrict__ cond, const float* __restrict__ w_ada,
    float* __restrict__ ss)
{
  const int lane = threadIdx.x & 63;
  const int gw = blockIdx.x * 4 + (threadIdx.x >> 6);
  const int b = gw >> 12;
  const int j = gw & 4095;
  const float4* wr = (const float4*)(w_ada + j * 2048);
  const float4* cr = (const float4*)(cond + b * 2048);
  float acc = 0.f;
  #pragma unroll
  for (int k4 = 0; k4 < 8; ++k4) {
    float4 w = wr[lane + k4 * 64];
    float4 c = cr[lane + k4 * 64];
    acc += w.x * c.x + w.y * c.y + w.z * c.z + w.w * c.w;
  }
  #pragma unroll
  for (int off = 1; off < 64; off <<= 1) acc += __shfl_xor(acc, off);
  if (lane == 0) ss[b * 4096 + j] = acc;
}

// ---------------------------------------------------------------------------
// 2) AdaRMSNorm: h = rms_norm(x)*(1+scale) + shift, write bf16
// ---------------------------------------------------------------------------
__global__ __launch_bounds__(256) void ada_rms_kernel(
    const float* __restrict__ x, const float* __restrict__ ss,
    unsigned short* __restrict__ H)
{
  const int row = blockIdx.x;
  const int b = row >> 11;
  const int tid = threadIdx.x;
  const int lane = tid & 63, wave = tid >> 6;
  const float* xr = x + (size_t)row * 2048;
  float4 v0 = ((const float4*)xr)[tid * 2];
  float4 v1 = ((const float4*)xr)[tid * 2 + 1];
  float ssq = v0.x*v0.x + v0.y*v0.y + v0.z*v0.z + v0.w*v0.w
            + v1.x*v1.x + v1.y*v1.y + v1.z*v1.z + v1.w*v1.w;
  #pragma unroll
  for (int off = 1; off < 64; off <<= 1) ssq += __shfl_xor(ssq, off);
  __shared__ float red[4];
  if (lane == 0) red[wave] = ssq;
  __syncthreads();
  const float tot = red[0] + red[1] + red[2] + red[3];
  const float r = rsqrtf(tot * (1.f / 2048.f) + EPS_F32);
  const int c0 = tid * 8;
  const float* sh = ss + b * 4096;
  float xv[8] = {v0.x, v0.y, v0.z, v0.w, v1.x, v1.y, v1.z, v1.w};
  unsigned int pk[4];
  #pragma unroll
  for (int p = 0; p < 4; ++p) {
    const int c = c0 + p * 2;
    float h0 = xv[p*2+0] * r * (1.f + sh[2048 + c])     + sh[c];
    float h1 = xv[p*2+1] * r * (1.f + sh[2048 + c + 1]) + sh[c + 1];
    pk[p] = (unsigned int)f2bf(h0) | ((unsigned int)f2bf(h1) << 16);
  }
  *(uint4*)&H[(size_t)row * 2048 + c0] = make_uint4(pk[0], pk[1], pk[2], pk[3]);
}

// ---------------------------------------------------------------------------
// 3) fp32 -> bf16 weight cast, both weights in one launch.
//    dst is contiguous: [w_qkv bf16 : 12582912][w_out bf16 : 4194304]
// ---------------------------------------------------------------------------
__global__ __launch_bounds__(256) void cast2_kernel(
    const float* __restrict__ a,   // w_qkv, 3145728 float4
    const float* __restrict__ b,   // w_out, 1048576 float4
    unsigned short* __restrict__ dst)
{
  const int i = blockIdx.x * 256 + threadIdx.x;   // 0..4194303
  float4 v = (i < 3145728) ? ((const float4*)a)[i]
                           : ((const float4*)b)[i - 3145728];
  unsigned int p0 = (unsigned int)f2bf(v.x) | ((unsigned int)f2bf(v.y) << 16);
  unsigned int p1 = (unsigned int)f2bf(v.z) | ((unsigned int)f2bf(v.w) << 16);
  *(uint2*)&dst[(size_t)i * 4] = make_uint2(p0, p1);
}

// ---------------------------------------------------------------------------
// 4a) QKV GEMM: 256x256 tile, BK=64, 8-phase schedule (8 waves = 2M x 4N).
//    M=4096, N=6144, K=2048 hardcoded. A=[M,K] bf16, Bw=[N,K] bf16.
//    Epilogue: q/k (bn<4096) get fused per-head RMSNorm(qk_w)+RoPE
//    (+QSCALE for q) before the bf16 store; v (bn>=4096) -> Vt scatter.
// ---------------------------------------------------------------------------
__global__ __launch_bounds__(512, 2) void gemm_qkv_8p(
    const unsigned short* __restrict__ A,
    const unsigned short* __restrict__ Bw,
    unsigned short* __restrict__ C,
    unsigned short* __restrict__ vt,
    const float* __restrict__ rope,
    const float* __restrict__ qk_w)
{
  __shared__ unsigned short As[2][2][8192];   // [buf][khalf][256 rows * 32 k]
  __shared__ unsigned short Bs[2][2][8192];

  const int tid  = threadIdx.x;
  const int lane = tid & 63;
  const int wave = tid >> 6;              // 0..7
  const int wrow = (wave >> 2) * 128;     // 0 / 128
  const int wcol = (wave & 3) * 64;       // 0 / 64 / 128 / 192

  // bijective XCD chunk swizzle (384 % 8 == 0)
  const int swz = (blockIdx.x & 7) * 48 + (blockIdx.x >> 3);
  const int bx = swz >> 4;                // 0..23  (N tiles)
  const int by = swz & 15;                // 0..15  (M tiles)
  const int bm = by * 256;
  const int bn = bx * 256;

  const int fr = lane & 15;
  const int q_ = lane >> 4;
  const int laneoff = fr * 32 + ((q_ ^ ((fr >> 1) & 3)) << 3);

  const int rA  = wave * 32 + (lane >> 2);            // j=0 row (j=1: +16)
  const int kk  = (lane & 3) ^ ((lane >> 3) & 3);     // inverse-swizzled k-octet
  const unsigned short* Ag0 = A  + (size_t)(bm + rA) * 2048 + kk * 8;
  const unsigned short* Ag1 = Ag0 + (size_t)16 * 2048;
  const unsigned short* Bg0 = Bw + (size_t)(bn + rA) * 2048 + kk * 8;
  const unsigned short* Bg1 = Bg0 + (size_t)16 * 2048;
  const int ldso = rA * 32 + (lane & 3) * 8;          // linear LDS dest (j=1: +512)

  f32x4 acc[8][4] = {};
  bf16x8 fA[4], fB[4];

#define STAGE_A(SB, SKH, KT) do { \
    gload16(Ag0 + (KT) * 64 + (SKH) * 32, &As[SB][SKH][ldso]); \
    gload16(Ag1 + (KT) * 64 + (SKH) * 32, &As[SB][SKH][ldso + 512]); } while (0)
#define STAGE_B(SB, SKH, KT) do { \
    gload16(Bg0 + (KT) * 64 + (SKH) * 32, &Bs[SB][SKH][ldso]); \
    gload16(Bg1 + (KT) * 64 + (SKH) * 32, &Bs[SB][SKH][ldso + 512]); } while (0)
#define VMW(N) asm volatile("s_waitcnt vmcnt(" #N ")" ::: "memory")
#define LDB(BUF, KH) do { const unsigned short* p_ = &Bs[BUF][KH][wcol * 32 + laneoff]; \
    fB[0] = *(const bf16x8*)&p_[0];    fB[1] = *(const bf16x8*)&p_[512]; \
    fB[2] = *(const bf16x8*)&p_[1024]; fB[3] = *(const bf16x8*)&p_[1536]; } while (0)
#define LDA(BUF, KH, MH) do { const unsigned short* p_ = &As[BUF][KH][(wrow + (MH) * 64) * 32 + laneoff]; \
    fA[0] = *(const bf16x8*)&p_[0];    fA[1] = *(const bf16x8*)&p_[512]; \
    fA[2] = *(const bf16x8*)&p_[1024]; fA[3] = *(const bf16x8*)&p_[1536]; } while (0)
#define MFMA16(MH) do { \
    _Pragma("unroll") \
    for (int f_ = 0; f_ < 4; ++f_) { \
      _Pragma("unroll") \
      for (int n_ = 0; n_ < 4; ++n_) \
        acc[(MH) * 4 + f_][n_] = __builtin_amdgcn_mfma_f32_16x16x32_bf16( \
            fA[f_], fB[n_], acc[(MH) * 4 + f_][n_], 0, 0, 0); \
    } } while (0)
#define PH_MID() do { __builtin_amdgcn_s_barrier(); \
    asm volatile("s_waitcnt lgkmcnt(0)"); \
    __builtin_amdgcn_s_setprio(1); } while (0)
#define PH_END() do { __builtin_amdgcn_s_setprio(0); \
    __builtin_amdgcn_s_barrier(); } while (0)

  // prologue: stage K-tile 0 into buf0 (order Ak0, Bk0, Ak1, Bk1)
  STAGE_A(0, 0, 0); STAGE_B(0, 0, 0); STAGE_A(0, 1, 0); STAGE_B(0, 1, 0);
  VMW(4);                      // Ak0+Bk0 landed; Ak1+Bk1 still in flight
  __builtin_amdgcn_s_barrier();

  for (int it = 0; it < 16; ++it) {
    const int t1 = 2 * it + 1;
    const int t2 = 2 * it + 2;
    const bool pf = (it < 15);

    // ---- K-tile 2it (buf0); stage K-tile 2it+1 -> buf1 ----
    LDB(0, 0); LDA(0, 0, 0);
    STAGE_A(1, 0, t1);
    PH_MID(); MFMA16(0); PH_END();
    LDA(0, 0, 1);
    STAGE_B(1, 0, t1);
    VMW(4);                    // retire prev P7/P8 (buf0 Ak1,Bk1) for P3
    PH_MID(); MFMA16(1); PH_END();
    LDB(0, 1); LDA(0, 1, 0);
    STAGE_A(1, 1, t1);
    PH_MID(); MFMA16(0); PH_END();
    LDA(0, 1, 1);
    STAGE_B(1, 1, t1);
    VMW(4);                    // retire P1/P2 (buf1 Ak0,Bk0) for P5
    PH_MID(); MFMA16(1); PH_END();

    // ---- K-tile 2it+1 (buf1); stage K-tile 2it+2 -> buf0 ----
    LDB(1, 0); LDA(1, 0, 0);
    if (pf) STAGE_A(0, 0, t2);
    PH_MID(); MFMA16(0); PH_END();
    LDA(1, 0, 1);
    if (pf) { STAGE_B(0, 0, t2); VMW(4); }  // retire P3/P4 (buf1 Ak1,Bk1)
    else    { VMW(0); }                     // last iter: drain P3/P4
    PH_MID(); MFMA16(1); PH_END();
    LDB(1, 1); LDA(1, 1, 0);
    if (pf) STAGE_A(0, 1, t2);
    PH_MID(); MFMA16(0); PH_END();
    LDA(1, 1, 1);
    if (pf) STAGE_B(0, 1, t2);
    VMW(4);                    // retire P5/P6 (buf0 Ak0,Bk0) for next P1
    PH_MID(); MFMA16(1); PH_END();
  }

#undef STAGE_A
#undef STAGE_B
#undef VMW
#undef LDB
#undef LDA
#undef MFMA16
#undef PH_MID
#undef PH_END

  // epilogue: per-wave 128x64 C block. bn multiple of 256 -> each wave's
  // 64-col span is one full head (heads are 64-wide), purely q, k, or v.
  const int cr = (lane >> 4) * 4;
  const int cc = lane & 15;
  if (bn >= 4096) {
    // v third -> Vt scatter (transposed + k-permuted), unchanged
    #pragma unroll
    for (int mf = 0; mf < 8; ++mf)
      #pragma unroll
      for (int nf = 0; nf < 4; ++nf)
        #pragma unroll
        for (int r = 0; r < 4; ++r) {
          const int m  = bm + wrow + mf * 16 + cr + r;
          const int dg = bn + wcol + nf * 16 + cc - 4096;
          const int l  = m & 2047;
          const size_t dst = ((size_t)((m >> 11) * 32 + (dg >> 6)) * 64 + (dg & 63)) * 2048
                           + (l >> 6) * 64 + (l & 15) * 4 + ((l >> 4) & 3);
          vt[dst] = f2bf(acc[mf][nf][r]);
        }
  } else {
    // q/k: fused per-head RMSNorm(qk_w) + RoPE (+QSCALE for q).
    // Row's 64 dims live in this 16-lane cc-group: 4 per lane (nf) x 16 cc.
    const bool is_q = (bn + wcol) < 2048;         // wave-uniform
    const float qs = is_q ? QSCALE : 1.0f;
    float w4[4];
    #pragma unroll
    for (int nf = 0; nf < 4; ++nf) w4[nf] = qk_w[nf * 16 + cc];
    #pragma unroll
    for (int mf = 0; mf < 8; ++mf)
      #pragma unroll
      for (int r = 0; r < 4; ++r) {
        const int row = bm + wrow + mf * 16 + cr + r;
        const int l = row & 2047;
        float ssq = 0.f;
        #pragma unroll
        for (int nf = 0; nf < 4; ++nf) { const float v = acc[mf][nf][r]; ssq += v * v; }
        ssq += __shfl_xor(ssq, 1);
        ssq += __shfl_xor(ssq, 2);
        ssq += __shfl_xor(ssq, 4);
        ssq += __shfl_xor(ssq, 8);                // sum over 16 cc lanes (same cr)
        const float rn = rsqrtf(ssq * (1.f / 64.f) + EPS_F32) * qs;
        const float* rp0 = rope + l * 64 + cc;
        const float* rp1 = rp0 + 131072;
        #pragma unroll
        for (int nf = 0; nf < 4; ++nf) {
          const float vn = acc[mf][nf][r] * rn * w4[nf];
          const float vp = __shfl_xor(vn, 1);     // partner dim d^1 at lane cc^1
          const float vh = (cc & 1) ? vp : -vp;   // x_hat = (-x_odd, x_even)
          const float o = vn * rp0[nf * 16] + vh * rp1[nf * 16];
          C[(size_t)row * 6144 + bn + wcol + nf * 16 + cc] = f2bf(o);
        }
      }
  }
}

// ---------------------------------------------------------------------------
// 4b) out-projection GEMM: 256x128 tile, BK=64, 4-phase schedule,
//    512 threads (8 waves = 4M x 2N, 64x64 out each). grid 16x16 = 256
//    blocks = exactly 1/CU, no tail. Same LDS XOR-swizzle + counted-vmcnt
//    discipline as the QKV 8p kernel (uniform: issue 3 loads, vmcnt(3)).
//    A = attn O [4096][2048] bf16, Bw = w_out [2048][2048] bf16, C f32.
// ---------------------------------------------------------------------------
__global__ __launch_bounds__(512, 1) void gemm_out_4p(
    const unsigned short* __restrict__ A,
    const unsigned short* __restrict__ Bw,
    float* __restrict__ C)
{
  __shared__ unsigned short As[2][2][8192];   // [buf][khalf][256 rows * 32 k]
  __shared__ unsigned short Bs[2][2][4096];   // [buf][khalf][128 rows * 32 k]

  const int tid  = threadIdx.x;
  const int lane = tid & 63;
  const int wave = tid >> 6;              // 0..7
  const int wrow = (wave >> 1) * 64;      // 0/64/128/192
  const int wcol = (wave & 1) * 64;       // 0/64

  // bijective XCD chunk swizzle (256 % 8 == 0, 32 blocks per XCD)
  const int swz = (blockIdx.x & 7) * 32 + (blockIdx.x >> 3);
  const int bx = swz >> 4;                // 0..15 (N tiles of 128)
  const int by = swz & 15;                // 0..15 (M tiles of 256)
  const int bm = by * 256;
  const int bn = bx * 128;

  const int fr = lane & 15;
  const int q_ = lane >> 4;
  const int laneoff = fr * 32 + ((q_ ^ ((fr >> 1) & 3)) << 3);

  const int rA = wave * 32 + (lane >> 2);             // A rows (j=1: +16)
  const int rB = wave * 16 + (lane >> 2);             // B rows
  const int kk = (lane & 3) ^ ((lane >> 3) & 3);      // inverse-swizzled k-octet
  const unsigned short* Ag0 = A  + (size_t)(bm + rA) * 2048 + kk * 8;
  const unsigned short* Ag1 = Ag0 + (size_t)16 * 2048;
  const unsigned short* Bg0 = Bw + (size_t)(bn + rB) * 2048 + kk * 8;
  const int ldsoA = rA * 32 + (lane & 3) * 8;
  const int ldsoB = rB * 32 + (lane & 3) * 8;

  f32x4 acc[4][4] = {};
  bf16x8 fA[4], fB[4];

#define STAGE_A4(SB, SKH, KT) do { \
    gload16(Ag0 + (KT) * 64 + (SKH) * 32, &As[SB][SKH][ldsoA]); \
    gload16(Ag1 + (KT) * 64 + (SKH) * 32, &As[SB][SKH][ldsoA + 512]); } while (0)
#define STAGE_B4(SB, SKH, KT) \
    gload16(Bg0 + (KT) * 64 + (SKH) * 32, &Bs[SB][SKH][ldsoB])
#define VMW(N) asm volatile("s_waitcnt vmcnt(" #N ")" ::: "memory")
#define LDB4(BUF, KH) do { const unsigned short* p_ = &Bs[BUF][KH][wcol * 32 + laneoff]; \
    fB[0] = *(const bf16x8*)&p_[0];    fB[1] = *(const bf16x8*)&p_[512]; \
    fB[2] = *(const bf16x8*)&p_[1024]; fB[3] = *(const bf16x8*)&p_[1536]; } while (0)
#define LDA4(BUF, KH) do { const unsigned short* p_ = &As[BUF][KH][wrow * 32 + laneoff]; \
    fA[0] = *(const bf16x8*)&p_[0];    fA[1] = *(const bf16x8*)&p_[512]; \
    fA[2] = *(const bf16x8*)&p_[1024]; fA[3] = *(const bf16x8*)&p_[1536]; } while (0)
#define MFMA16_4() do { \
    _Pragma("unroll") \
    for (int f_ = 0; f_ < 4; ++f_) { \
      _Pragma("unroll") \
      for (int n_ = 0; n_ < 4; ++n_) \
        acc[f_][n_] = __builtin_amdgcn_mfma_f32_16x16x32_bf16( \
            fA[f_], fB[n_], acc[f_][n_], 0, 0, 0); \
    } } while (0)
#define PH_MID() do { __builtin_amdgcn_s_barrier(); \
    asm volatile("s_waitcnt lgkmcnt(0)"); \
    __builtin_amdgcn_s_setprio(1); } while (0)
#define PH_END() do { __builtin_amdgcn_s_setprio(0); \
    __builtin_amdgcn_s_barrier(); } while (0)

  // prologue: stage K-tile 0 (k0 batch: A 2 loads + B 1; then k1 batch)
  STAGE_A4(0, 0, 0); STAGE_B4(0, 0, 0);
  STAGE_A4(0, 1, 0); STAGE_B4(0, 1, 0);
  VMW(3);                      // k0 batch landed; k1 batch in flight
  __builtin_amdgcn_s_barrier();

  for (int it = 0; it < 16; ++it) {
    const int t1 = 2 * it + 1;
    const int t2 = 2 * it + 2;
    const bool pf = (it < 15);

    // ---- K-tile 2it (buf0); stage K-tile 2it+1 -> buf1 ----
    LDB4(0, 0); LDA4(0, 0);
    STAGE_A4(1, 0, t1); STAGE_B4(1, 0, t1);
    VMW(3);                    // retire prev tile's k1 batch (read next phase)
    PH_MID(); MFMA16_4(); PH_END();
    LDB4(0, 1); LDA4(0, 1);
    STAGE_A4(1, 1, t1); STAGE_B4(1, 1, t1);
    VMW(3);                    // retire buf1-k0 batch
    PH_MID(); MFMA16_4(); PH_END();

    // ---- K-tile 2it+1 (buf1); stage K-tile 2it+2 -> buf0 ----
    LDB4(1, 0); LDA4(1, 0);
    if (pf) { STAGE_A4(0, 0, t2); STAGE_B4(0, 0, t2); VMW(3); }
    else    { VMW(0); }
    PH_MID(); MFMA16_4(); PH_END();
    LDB4(1, 1); LDA4(1, 1);
    if (pf) { STAGE_A4(0, 1, t2); STAGE_B4(0, 1, t2); VMW(3); }
    else    { VMW(0); }
    PH_MID(); MFMA16_4(); PH_END();
  }

#undef STAGE_A4
#undef STAGE_B4
#undef VMW
#undef LDB4
#undef LDA4
#undef MFMA16_4
#undef PH_MID
#undef PH_END

  // epilogue: f32 C write, per wave 64x64 block
  const int cr = (lane >> 4) * 4;
  const int cc = lane & 15;
  #pragma unroll
  for (int f = 0; f < 4; ++f)
    #pragma unroll
    for (int n = 0; n < 4; ++n)
      #pragma unroll
      for (int r = 0; r < 4; ++r) {
        const int row = bm + wrow + f * 16 + cr + r;
        const int col = bn + wcol + n * 16 + cc;
        C[(size_t)row * 2048 + col] = acc[f][n][r];
      }
}

// ---------------------------------------------------------------------------
// 5) MFMA flash attention (no-max softmax). 64q/wave, 256q/block, k-tile 64.
//    (verified R4 structure: plain two-barrier staging, no prefetch/setprio)
// ---------------------------------------------------------------------------
__global__ __launch_bounds__(256, 2) void attn_mfma_kernel(
    const unsigned short* __restrict__ QKV,  // [4096][6144] (q,k roped)
    const unsigned short* __restrict__ Vt,   // [64 bh][64 d][2048 k-perm]
    unsigned short* __restrict__ O)          // [4096][2048]
{
  __shared__ unsigned short Ks[64 * 72];
  __shared__ unsigned short Vs[64 * 72];
  __shared__ unsigned short Ps[4 * 64 * 68];
  const int tid  = threadIdx.x;
  const int lane = tid & 63;
  const int wave = tid >> 6;
  const int blk = blockIdx.x;              // 0..511
  const int bh = blk & 63;                 // blk%8 == bh%8 -> XCD-affine
  const int qt = blk >> 6;                 // 0..7
  const int b = bh >> 5, h = bh & 31;
  const int rowbase = b << 11;
  const int qbase = qt * 256 + wave * 64;  // 64 q rows per wave

  const int m16  = lane & 15;
  const int quad = lane >> 4;
  const int m32  = lane & 31;
  const int hl   = lane >> 5;

  // Q fragments (already scaled by QSCALE in fused epilogue): 4 x 16-row tiles
  bf16x8 qf[4][2];
  #pragma unroll
  for (int qi = 0; qi < 4; ++qi)
    #pragma unroll
    for (int ch = 0; ch < 2; ++ch)
      qf[qi][ch] = *(const bf16x8*)&QKV[(size_t)(rowbase + qbase + qi * 16 + m16) * 6144
                                        + h * 64 + ch * 32 + quad * 8];

  const int sr = tid >> 2;            // staging row 0..63
  const int sc = (tid & 3) * 16;      // staging col (shorts)
  const unsigned short* Kg = QKV + (size_t)(rowbase + sr) * 6144 + 2048 + h * 64 + sc;
  const unsigned short* Vg = Vt + (size_t)(bh * 64 + sr) * 2048 + sc;

  f32x16 accO[2][2] = {};                 // [q-subtile 32][d-tile 32]
  float part[4][4] = {};                  // per-16-row-tile row sums
  unsigned short* Pw = &Ps[(wave * 64) * 68];

  for (int kt = 0; kt < 32; ++kt) {
    __syncthreads();
    {
      const uint4* kp = (const uint4*)(Kg + (size_t)kt * 64 * 6144);
      const uint4* vp = (const uint4*)(Vg + kt * 64);
      uint4 k0 = kp[0], k1 = kp[1];
      uint4 v0 = vp[0], v1 = vp[1];
      *(uint4*)&Ks[sr * 72 + sc]     = k0;
      *(uint4*)&Ks[sr * 72 + sc + 8] = k1;
      *(uint4*)&Vs[sr * 72 + sc]     = v0;
      *(uint4*)&Vs[sr * 72 + sc + 8] = v1;
    }
    __syncthreads();

    // S (16x16x32) -> exp2 -> pack P (key perm p = c*4 + kj)
    unsigned int pk[4][4][2];
    #pragma unroll
    for (int kj = 0; kj < 4; ++kj) {
      bf16x8 kf0 = *(const bf16x8*)&Ks[(kj * 16 + m16) * 72 + quad * 8];
      bf16x8 kf1 = *(const bf16x8*)&Ks[(kj * 16 + m16) * 72 + 32 + quad * 8];
      #pragma unroll
      for (int qi = 0; qi < 4; ++qi) {
        f32x4 acc = {};
        acc = __builtin_amdgcn_mfma_f32_16x16x32_bf16(qf[qi][0], kf0, acc, 0, 0, 0);
        acc = __builtin_amdgcn_mfma_f32_16x16x32_bf16(qf[qi][1], kf1, acc, 0, 0, 0);
        #pragma unroll
        for (int r = 0; r < 4; ++r) {
          float p = EXP2F(acc[r]);
          part[qi][r] += p;
          unsigned int pb = f2bf_rn_u(p);
          if (kj == 0)      pk[qi][r][0]  = pb >> 16;
          else if (kj == 1) pk[qi][r][0] |= pb & 0xffff0000u;
          else if (kj == 2) pk[qi][r][1]  = pb >> 16;
          else              pk[qi][r][1] |= pb & 0xffff0000u;
        }
      }
    }
    #pragma unroll
    for (int qi = 0; qi < 4; ++qi)
      #pragma unroll
      for (int r = 0; r < 4; ++r)
        *(uint2*)&Pw[(qi * 16 + quad * 4 + r) * 68 + m16 * 4] =
            make_uint2(pk[qi][r][0], pk[qi][r][1]);
    // wave-private P region: RAW covered by lgkmcnt, no barrier

    // PV (32x32x16): accO[qs][dt], vb reused across qs
    #pragma unroll
    for (int ch = 0; ch < 4; ++ch) {
      bf16x8 pa0 = *(const bf16x8*)&Pw[m32 * 68 + ch * 16 + hl * 8];
      bf16x8 pa1 = *(const bf16x8*)&Pw[(32 + m32) * 68 + ch * 16 + hl * 8];
      bf16x8 vb0 = *(const bf16x8*)&Vs[m32 * 72 + ch * 16 + hl * 8];
      bf16x8 vb1 = *(const bf16x8*)&Vs[(32 + m32) * 72 + ch * 16 + hl * 8];
      accO[0][0] = __builtin_amdgcn_mfma_f32_32x32x16_bf16(pa0, vb0, accO[0][0], 0, 0, 0);
      accO[0][1] = __builtin_amdgcn_mfma_f32_32x32x16_bf16(pa0, vb1, accO[0][1], 0, 0, 0);
      accO[1][0] = __builtin_amdgcn_mfma_f32_32x32x16_bf16(pa1, vb0, accO[1][0], 0, 0, 0);
      accO[1][1] = __builtin_amdgcn_mfma_f32_32x32x16_bf16(pa1, vb1, accO[1][1], 0, 0, 0);
    }
  }

  // reduce row sums over the 16 n-lanes
  #pragma unroll
  for (int qi = 0; qi < 4; ++qi)
    #pragma unroll
    for (int r = 0; r < 4; ++r)
      #pragma unroll
      for (int off = 1; off < 16; off <<= 1)
        part[qi][r] += __shfl_xor(part[qi][r], off);

  // epilogue: per 32-row q-subtile, gather row sum, divide, store
  #pragma unroll
  for (int qs = 0; qs < 2; ++qs) {
    #pragma unroll
    for (int reg = 0; reg < 16; ++reg) {
      const int r = reg & 3;
      const int s = reg >> 2;
      const int qsrc = ((2 * s + hl) & 3) * 16 + m16;
      const float rs = __shfl(part[qs * 2 + (reg >> 3)][r], qsrc);
      const float inv = RCPF(rs);
      const int rho = r + 8 * s + 4 * hl;      // row in 32x32 C layout
      const size_t base = (size_t)(rowbase + qbase + qs * 32 + rho) * 2048 + h * 64;
      O[base + m32]      = f2bf(accO[qs][0][reg] * inv);
      O[base + 32 + m32] = f2bf(accO[qs][1][reg] * inv);
    }
  }
}

// ---------------------------------------------------------------------------
// launch
// ---------------------------------------------------------------------------
extern "C" void kernel_launch(void* const* d_in, const int* in_sizes, int n_in,
                              void* d_out, int out_size, void* d_ws, size_t ws_size,
                              hipStream_t stream) {
  (void)in_sizes; (void)n_in; (void)out_size; (void)ws_size;
  const float* x     = (const float*)d_in[0];
  const float* cond  = (const float*)d_in[1];
  const float* rope  = (const float*)d_in[2];
  const float* w_ada = (const float*)d_in[3];
  const float* w_qkv = (const float*)d_in[4];
  const float* w_out = (const float*)d_in[5];
  const float* qk_w  = (const float*)d_in[6];
  float* out = (float*)d_out;

  char* ws = (char*)d_ws;
  float*          ss   = (float*)ws;                       // 32 KB
  unsigned short* H    = (unsigned short*)(ws + 32768);    // 16 MB, reused as O
  unsigned short* Wq   = H + 8388608;                      // 24 MB
  unsigned short* Wo   = Wq + 12582912;                    // 8 MB  (contiguous after Wq)
  unsigned short* QKV  = Wo + 4194304;                     // 48 MB (q,k used)
  unsigned short* Vt_g = QKV + 25165824;                   // 16 MB

  ada_gemm_kernel<<<2048, 256, 0, stream>>>(cond, w_ada, ss);
  ada_rms_kernel<<<4096, 256, 0, stream>>>(x, ss, H);
  cast2_kernel<<<16384, 256, 0, stream>>>(w_qkv, w_out, Wq);
  // qkv = H @ w_qkv^T ; q,k -> QKV (RMS+RoPE fused), v -> Vt_g (transposed)
  gemm_qkv_8p<<<384, 512, 0, stream>>>(H, Wq, QKV, Vt_g, rope, qk_w);
  attn_mfma_kernel<<<512, 256, 0, stream>>>(QKV, Vt_g, H);
  gemm_out_4p<<<256, 512, 0, stream>>>(H, Wo, out);
}

// Round 9
// 443.735 us; speedup vs baseline: 1.0791x; 1.0087x over previous
//
#include <hip/hip_runtime.h>

// ---------------------------------------------------------------------------
// Attention_17703855194398: AdaRMSNorm -> QKV -> per-head RMS+RoPE -> SDPA -> out
// B=2, L=2048, D=2048, NH=32, HD=64, DC=2048
// R12: QKV GEMM re-tiled 256x128 / 4-phase / grid 768 = 3 perfectly balanced
//      rounds at 1 block/CU (R11 post-mortem: 384 blocks = 1.5 rounds, half
//      the machine idle in round 2). Rope UN-fused (fused epilogue cost ~20us
//      vs the 9us dispatch it saved) -> R8-verified vectorized qk_rope_kernel.
//      attn + out-proj unchanged.
// ---------------------------------------------------------------------------

typedef __bf16 bf16x8 __attribute__((ext_vector_type(8)));
typedef float  f32x4  __attribute__((ext_vector_type(4)));
typedef float  f32x16 __attribute__((ext_vector_type(16)));

#define EPS_F32 1.1920929e-07f
// q prescale: (1/sqrt(64)) * log2(e)  -> scores land in exp2 domain
#define QSCALE 0.18033688011112042f

#if defined(__has_builtin)
#  if __has_builtin(__builtin_amdgcn_exp2f)
#    define EXP2F(x) __builtin_amdgcn_exp2f(x)
#  else
#    define EXP2F(x) __expf((x) * 0.6931471805599453f)
#  endif
#  if __has_builtin(__builtin_amdgcn_rcpf)
#    define RCPF(x) __builtin_amdgcn_rcpf(x)
#  else
#    define RCPF(x) (1.0f / (x))
#  endif
#else
#  define EXP2F(x) __expf((x) * 0.6931471805599453f)
#  define RCPF(x) (1.0f / (x))
#endif

__device__ __forceinline__ float bf2f(unsigned int u16) {
  union { unsigned int i; float f; } v; v.i = (u16 & 0xffffu) << 16; return v.f;
}
__device__ __forceinline__ float bf2f_hi(unsigned int u32) {
  union { unsigned int i; float f; } v; v.i = u32 & 0xffff0000u; return v.f;
}
__device__ __forceinline__ unsigned short f2bf(float f) {
  union { float f; unsigned int i; } v; v.f = f;
  unsigned int r = v.i + 0x7fffu + ((v.i >> 16) & 1u);  // RNE
  return (unsigned short)(r >> 16);
}
// round-to-nearest (ties away) bf16 bits, cheap: 2 ops
__device__ __forceinline__ unsigned int f2bf_rn_u(float f) {
  union { float f; unsigned int i; } v; v.f = f;
  return v.i + 0x8000u;   // caller takes >>16 or &0xffff0000
}

// async global->LDS, 16B per lane (wave-uniform base + lane*16)
__device__ __forceinline__ void gload16(const void* g, void* l) {
  __builtin_amdgcn_global_load_lds(
      (const __attribute__((address_space(1))) unsigned int*)(unsigned long long)g,
      (__attribute__((address_space(3))) unsigned int*)(unsigned int)(unsigned long long)l,
      16, 0, 0);
}

// ---------------------------------------------------------------------------
// 1) ada GEMM: ss[b,j] = sum_k cond[b,k] * w_ada[j,k]
// ---------------------------------------------------------------------------
__global__ __launch_bounds__(256) void ada_gemm_kernel(
    const float* __restrict__ cond, const float* __restrict__ w_ada,
    float* __restrict__ ss)
{
  const int lane = threadIdx.x & 63;
  const int gw = blockIdx.x * 4 + (threadIdx.x >> 6);
  const int b = gw >> 12;
  const int j = gw & 4095;
  const float4* wr = (const float4*)(w_ada + j * 2048);
  const float4* cr = (const float4*)(cond + b * 2048);
  float acc = 0.f;
  #pragma unroll
  for (int k4 = 0; k4 < 8; ++k4) {
    float4 w = wr[lane + k4 * 64];
    float4 c = cr[lane + k4 * 64];
    acc += w.x * c.x + w.y * c.y + w.z * c.z + w.w * c.w;
  }
  #pragma unroll
  for (int off = 1; off < 64; off <<= 1) acc += __shfl_xor(acc, off);
  if (lane == 0) ss[b * 4096 + j] = acc;
}

// ---------------------------------------------------------------------------
// 2) AdaRMSNorm: h = rms_norm(x)*(1+scale) + shift, write bf16
// ---------------------------------------------------------------------------
__global__ __launch_bounds__(256) void ada_rms_kernel(
    const float* __restrict__ x, const float* __restrict__ ss,
    unsigned short* __restrict__ H)
{
  const int row = blockIdx.x;
  const int b = row >> 11;
  const int tid = threadIdx.x;
  const int lane = tid & 63, wave = tid >> 6;
  const float* xr = x + (size_t)row * 2048;
  float4 v0 = ((const float4*)xr)[tid * 2];
  float4 v1 = ((const float4*)xr)[tid * 2 + 1];
  float ssq = v0.x*v0.x + v0.y*v0.y + v0.z*v0.z + v0.w*v0.w
            + v1.x*v1.x + v1.y*v1.y + v1.z*v1.z + v1.w*v1.w;
  #pragma unroll
  for (int off = 1; off < 64; off <<= 1) ssq += __shfl_xor(ssq, off);
  __shared__ float red[4];
  if (lane == 0) red[wave] = ssq;
  __syncthreads();
  const float tot = red[0] + red[1] + red[2] + red[3];
  const float r = rsqrtf(tot * (1.f / 2048.f) + EPS_F32);
  const int c0 = tid * 8;
  const float* sh = ss + b * 4096;
  float xv[8] = {v0.x, v0.y, v0.z, v0.w, v1.x, v1.y, v1.z, v1.w};
  unsigned int pk[4];
  #pragma unroll
  for (int p = 0; p < 4; ++p) {
    const int c = c0 + p * 2;
    float h0 = xv[p*2+0] * r * (1.f + sh[2048 + c])     + sh[c];
    float h1 = xv[p*2+1] * r * (1.f + sh[2048 + c + 1]) + sh[c + 1];
    pk[p] = (unsigned int)f2bf(h0) | ((unsigned int)f2bf(h1) << 16);
  }
  *(uint4*)&H[(size_t)row * 2048 + c0] = make_uint4(pk[0], pk[1], pk[2], pk[3]);
}

// ---------------------------------------------------------------------------
// 3) fp32 -> bf16 weight cast, both weights in one launch.
//    dst is contiguous: [w_qkv bf16 : 12582912][w_out bf16 : 4194304]
// ---------------------------------------------------------------------------
__global__ __launch_bounds__(256) void cast2_kernel(
    const float* __restrict__ a,   // w_qkv, 3145728 float4
    const float* __restrict__ b,   // w_out, 1048576 float4
    unsigned short* __restrict__ dst)
{
  const int i = blockIdx.x * 256 + threadIdx.x;   // 0..4194303
  float4 v = (i < 3145728) ? ((const float4*)a)[i]
                           : ((const float4*)b)[i - 3145728];
  unsigned int p0 = (unsigned int)f2bf(v.x) | ((unsigned int)f2bf(v.y) << 16);
  unsigned int p1 = (unsigned int)f2bf(v.z) | ((unsigned int)f2bf(v.w) << 16);
  *(uint2*)&dst[(size_t)i * 4] = make_uint2(p0, p1);
}

// ---------------------------------------------------------------------------
// 4a) QKV GEMM: 256x128 tile, BK=64, 4-phase schedule, 512 threads
//    (8 waves = 4M x 2N, 64x64 out each). grid 768 = exactly 3 balanced
//    rounds at 1 block/CU (96 KB LDS). M=4096, N=6144, K=2048 hardcoded.
//    Epilogue: q/k (bn<4096) plain bf16; v (bn>=4096) -> Vt scatter.
// ---------------------------------------------------------------------------
__global__ __launch_bounds__(512, 1) void gemm_qkv_4p(
    const unsigned short* __restrict__ A,
    const unsigned short* __restrict__ Bw,
    unsigned short* __restrict__ C,
    unsigned short* __restrict__ vt)
{
  __shared__ unsigned short As[2][2][8192];   // [buf][khalf][256 rows * 32 k]
  __shared__ unsigned short Bs[2][2][4096];   // [buf][khalf][128 rows * 32 k]

  const int tid  = threadIdx.x;
  const int lane = tid & 63;
  const int wave = tid >> 6;              // 0..7
  const int wrow = (wave >> 1) * 64;      // 0/64/128/192
  const int wcol = (wave & 1) * 64;       // 0/64

  // bijective XCD chunk swizzle (768 % 8 == 0, 96 blocks/XCD, bx-major:
  // each XCD keeps 6 B-panels (1.5 MB) hot in its private L2)
  const int swz = (blockIdx.x & 7) * 96 + (blockIdx.x >> 3);
  const int bx = swz >> 4;                // 0..47 (N tiles of 128)
  const int by = swz & 15;                // 0..15 (M tiles of 256)
  const int bm = by * 256;
  const int bn = bx * 128;

  const int fr = lane & 15;
  const int q_ = lane >> 4;
  const int laneoff = fr * 32 + ((q_ ^ ((fr >> 1) & 3)) << 3);

  const int rA = wave * 32 + (lane >> 2);             // A rows (2nd load: +16)
  const int rB = wave * 16 + (lane >> 2);             // B rows
  const int kk = (lane & 3) ^ ((lane >> 3) & 3);      // inverse-swizzled k-octet
  const unsigned short* Ag0 = A  + (size_t)(bm + rA) * 2048 + kk * 8;
  const unsigned short* Ag1 = Ag0 + (size_t)16 * 2048;
  const unsigned short* Bg0 = Bw + (size_t)(bn + rB) * 2048 + kk * 8;
  const int ldsoA = rA * 32 + (lane & 3) * 8;
  const int ldsoB = rB * 32 + (lane & 3) * 8;

  f32x4 acc[4][4] = {};
  bf16x8 fA[4], fB[4];

#define STAGE_A4(SB, SKH, KT) do { \
    gload16(Ag0 + (KT) * 64 + (SKH) * 32, &As[SB][SKH][ldsoA]); \
    gload16(Ag1 + (KT) * 64 + (SKH) * 32, &As[SB][SKH][ldsoA + 512]); } while (0)
#define STAGE_B4(SB, SKH, KT) \
    gload16(Bg0 + (KT) * 64 + (SKH) * 32, &Bs[SB][SKH][ldsoB])
#define VMW(N) asm volatile("s_waitcnt vmcnt(" #N ")" ::: "memory")
#define LDB4(BUF, KH) do { const unsigned short* p_ = &Bs[BUF][KH][wcol * 32 + laneoff]; \
    fB[0] = *(const bf16x8*)&p_[0];    fB[1] = *(const bf16x8*)&p_[512]; \
    fB[2] = *(const bf16x8*)&p_[1024]; fB[3] = *(const bf16x8*)&p_[1536]; } while (0)
#define LDA4(BUF, KH) do { const unsigned short* p_ = &As[BUF][KH][wrow * 32 + laneoff]; \
    fA[0] = *(const bf16x8*)&p_[0];    fA[1] = *(const bf16x8*)&p_[512]; \
    fA[2] = *(const bf16x8*)&p_[1024]; fA[3] = *(const bf16x8*)&p_[1536]; } while (0)
#define MFMA16_4() do { \
    _Pragma("unroll") \
    for (int f_ = 0; f_ < 4; ++f_) { \
      _Pragma("unroll") \
      for (int n_ = 0; n_ < 4; ++n_) \
        acc[f_][n_] = __builtin_amdgcn_mfma_f32_16x16x32_bf16( \
            fA[f_], fB[n_], acc[f_][n_], 0, 0, 0); \
    } } while (0)
#define PH_MID() do { __builtin_amdgcn_s_barrier(); \
    asm volatile("s_waitcnt lgkmcnt(0)"); \
    __builtin_amdgcn_s_setprio(1); } while (0)
#define PH_END() do { __builtin_amdgcn_s_setprio(0); \
    __builtin_amdgcn_s_barrier(); } while (0)

  // prologue: stage K-tile 0 (k0 batch: A 2 loads + B 1; then k1 batch)
  STAGE_A4(0, 0, 0); STAGE_B4(0, 0, 0);
  STAGE_A4(0, 1, 0); STAGE_B4(0, 1, 0);
  VMW(3);                      // k0 batch landed; k1 batch in flight
  __builtin_amdgcn_s_barrier();

  for (int it = 0; it < 16; ++it) {
    const int t1 = 2 * it + 1;
    const int t2 = 2 * it + 2;
    const bool pf = (it < 15);

    // ---- K-tile 2it (buf0); stage K-tile 2it+1 -> buf1 ----
    LDB4(0, 0); LDA4(0, 0);
    STAGE_A4(1, 0, t1); STAGE_B4(1, 0, t1);
    VMW(3);                    // retire prev tile's k1 batch (read next phase)
    PH_MID(); MFMA16_4(); PH_END();
    LDB4(0, 1); LDA4(0, 1);
    STAGE_A4(1, 1, t1); STAGE_B4(1, 1, t1);
    VMW(3);                    // retire buf1-k0 batch
    PH_MID(); MFMA16_4(); PH_END();

    // ---- K-tile 2it+1 (buf1); stage K-tile 2it+2 -> buf0 ----
    LDB4(1, 0); LDA4(1, 0);
    if (pf) { STAGE_A4(0, 0, t2); STAGE_B4(0, 0, t2); VMW(3); }
    else    { VMW(0); }
    PH_MID(); MFMA16_4(); PH_END();
    LDB4(1, 1); LDA4(1, 1);
    if (pf) { STAGE_A4(0, 1, t2); STAGE_B4(0, 1, t2); VMW(3); }
    else    { VMW(0); }
    PH_MID(); MFMA16_4(); PH_END();
  }

#undef STAGE_A4
#undef STAGE_B4
#undef VMW
#undef LDB4
#undef LDA4
#undef MFMA16_4
#undef PH_MID
#undef PH_END

  // epilogue: per-wave 64x64 block. bn multiple of 128 -> each wave's 64-col
  // span is one full head; q/k/v split is block-uniform.
  const int cr = (lane >> 4) * 4;
  const int cc = lane & 15;
  if (bn >= 4096) {
    // v third -> Vt scatter (transposed + k-permuted)
    #pragma unroll
    for (int mf = 0; mf < 4; ++mf)
      #pragma unroll
      for (int nf = 0; nf < 4; ++nf)
        #pragma unroll
        for (int r = 0; r < 4; ++r) {
          const int m  = bm + wrow + mf * 16 + cr + r;
          const int dg = bn + wcol + nf * 16 + cc - 4096;
          const int l  = m & 2047;
          const size_t dst = ((size_t)((m >> 11) * 32 + (dg >> 6)) * 64 + (dg & 63)) * 2048
                           + (l >> 6) * 64 + (l & 15) * 4 + ((l >> 4) & 3);
          vt[dst] = f2bf(acc[mf][nf][r]);
        }
  } else {
    #pragma unroll
    for (int mf = 0; mf < 4; ++mf)
      #pragma unroll
      for (int nf = 0; nf < 4; ++nf)
        #pragma unroll
        for (int r = 0; r < 4; ++r) {
          const int row = bm + wrow + mf * 16 + cr + r;
          const int col = bn + wcol + nf * 16 + cc;
          C[(size_t)row * 6144 + col] = f2bf(acc[mf][nf][r]);
        }
  }
}

// ---------------------------------------------------------------------------
// 4b) out-projection GEMM: 256x128 tile, BK=64, 4-phase schedule,
//    512 threads (8 waves = 4M x 2N). grid 256 = exactly 1 block/CU.
//    A = attn O [4096][2048] bf16, Bw = w_out [2048][2048] bf16, C f32.
// ---------------------------------------------------------------------------
__global__ __launch_bounds__(512, 1) void gemm_out_4p(
    const unsigned short* __restrict__ A,
    const unsigned short* __restrict__ Bw,
    float* __restrict__ C)
{
  __shared__ unsigned short As[2][2][8192];   // [buf][khalf][256 rows * 32 k]
  __shared__ unsigned short Bs[2][2][4096];   // [buf][khalf][128 rows * 32 k]

  const int tid  = threadIdx.x;
  const int lane = tid & 63;
  const int wave = tid >> 6;              // 0..7
  const int wrow = (wave >> 1) * 64;      // 0/64/128/192
  const int wcol = (wave & 1) * 64;       // 0/64

  // bijective XCD chunk swizzle (256 % 8 == 0, 32 blocks per XCD)
  const int swz = (blockIdx.x & 7) * 32 + (blockIdx.x >> 3);
  const int bx = swz >> 4;                // 0..15 (N tiles of 128)
  const int by = swz & 15;                // 0..15 (M tiles of 256)
  const int bm = by * 256;
  const int bn = bx * 128;

  const int fr = lane & 15;
  const int q_ = lane >> 4;
  const int laneoff = fr * 32 + ((q_ ^ ((fr >> 1) & 3)) << 3);

  const int rA = wave * 32 + (lane >> 2);             // A rows (2nd load: +16)
  const int rB = wave * 16 + (lane >> 2);             // B rows
  const int kk = (lane & 3) ^ ((lane >> 3) & 3);      // inverse-swizzled k-octet
  const unsigned short* Ag0 = A  + (size_t)(bm + rA) * 2048 + kk * 8;
  const unsigned short* Ag1 = Ag0 + (size_t)16 * 2048;
  const unsigned short* Bg0 = Bw + (size_t)(bn + rB) * 2048 + kk * 8;
  const int ldsoA = rA * 32 + (lane & 3) * 8;
  const int ldsoB = rB * 32 + (lane & 3) * 8;

  f32x4 acc[4][4] = {};
  bf16x8 fA[4], fB[4];

#define STAGE_A4(SB, SKH, KT) do { \
    gload16(Ag0 + (KT) * 64 + (SKH) * 32, &As[SB][SKH][ldsoA]); \
    gload16(Ag1 + (KT) * 64 + (SKH) * 32, &As[SB][SKH][ldsoA + 512]); } while (0)
#define STAGE_B4(SB, SKH, KT) \
    gload16(Bg0 + (KT) * 64 + (SKH) * 32, &Bs[SB][SKH][ldsoB])
#define VMW(N) asm volatile("s_waitcnt vmcnt(" #N ")" ::: "memory")
#define LDB4(BUF, KH) do { const unsigned short* p_ = &Bs[BUF][KH][wcol * 32 + laneoff]; \
    fB[0] = *(const bf16x8*)&p_[0];    fB[1] = *(const bf16x8*)&p_[512]; \
    fB[2] = *(const bf16x8*)&p_[1024]; fB[3] = *(const bf16x8*)&p_[1536]; } while (0)
#define LDA4(BUF, KH) do { const unsigned short* p_ = &As[BUF][KH][wrow * 32 + laneoff]; \
    fA[0] = *(const bf16x8*)&p_[0];    fA[1] = *(const bf16x8*)&p_[512]; \
    fA[2] = *(const bf16x8*)&p_[1024]; fA[3] = *(const bf16x8*)&p_[1536]; } while (0)
#define MFMA16_4() do { \
    _Pragma("unroll") \
    for (int f_ = 0; f_ < 4; ++f_) { \
      _Pragma("unroll") \
      for (int n_ = 0; n_ < 4; ++n_) \
        acc[f_][n_] = __builtin_amdgcn_mfma_f32_16x16x32_bf16( \
            fA[f_], fB[n_], acc[f_][n_], 0, 0, 0); \
    } } while (0)
#define PH_MID() do { __builtin_amdgcn_s_barrier(); \
    asm volatile("s_waitcnt lgkmcnt(0)"); \
    __builtin_amdgcn_s_setprio(1); } while (0)
#define PH_END() do { __builtin_amdgcn_s_setprio(0); \
    __builtin_amdgcn_s_barrier(); } while (0)

  // prologue: stage K-tile 0 (k0 batch: A 2 loads + B 1; then k1 batch)
  STAGE_A4(0, 0, 0); STAGE_B4(0, 0, 0);
  STAGE_A4(0, 1, 0); STAGE_B4(0, 1, 0);
  VMW(3);                      // k0 batch landed; k1 batch in flight
  __builtin_amdgcn_s_barrier();

  for (int it = 0; it < 16; ++it) {
    const int t1 = 2 * it + 1;
    const int t2 = 2 * it + 2;
    const bool pf = (it < 15);

    // ---- K-tile 2it (buf0); stage K-tile 2it+1 -> buf1 ----
    LDB4(0, 0); LDA4(0, 0);
    STAGE_A4(1, 0, t1); STAGE_B4(1, 0, t1);
    VMW(3);                    // retire prev tile's k1 batch (read next phase)
    PH_MID(); MFMA16_4(); PH_END();
    LDB4(0, 1); LDA4(0, 1);
    STAGE_A4(1, 1, t1); STAGE_B4(1, 1, t1);
    VMW(3);                    // retire buf1-k0 batch
    PH_MID(); MFMA16_4(); PH_END();

    // ---- K-tile 2it+1 (buf1); stage K-tile 2it+2 -> buf0 ----
    LDB4(1, 0); LDA4(1, 0);
    if (pf) { STAGE_A4(0, 0, t2); STAGE_B4(0, 0, t2); VMW(3); }
    else    { VMW(0); }
    PH_MID(); MFMA16_4(); PH_END();
    LDB4(1, 1); LDA4(1, 1);
    if (pf) { STAGE_A4(0, 1, t2); STAGE_B4(0, 1, t2); VMW(3); }
    else    { VMW(0); }
    PH_MID(); MFMA16_4(); PH_END();
  }

#undef STAGE_A4
#undef STAGE_B4
#undef VMW
#undef LDB4
#undef LDA4
#undef MFMA16_4
#undef PH_MID
#undef PH_END

  // epilogue: f32 C write, per wave 64x64 block
  const int cr = (lane >> 4) * 4;
  const int cc = lane & 15;
  #pragma unroll
  for (int f = 0; f < 4; ++f)
    #pragma unroll
    for (int n = 0; n < 4; ++n)
      #pragma unroll
      for (int r = 0; r < 4; ++r) {
        const int row = bm + wrow + f * 16 + cr + r;
        const int col = bn + wcol + n * 16 + cc;
        C[(size_t)row * 2048 + col] = acc[f][n][r];
      }
}

// ---------------------------------------------------------------------------
// 5) per-head RMSNorm(qk_w) + RoPE on q,k in place; q scaled by QSCALE.
//    Vectorized (R8): bf16x8 per lane, rotation lane-local, 3 shuffles per
//    8 elements, float4 table loads.
// ---------------------------------------------------------------------------
__global__ __launch_bounds__(256) void qk_rope_kernel(
    unsigned short* __restrict__ QKV, const float* __restrict__ rope,
    const float* __restrict__ qk_w)
{
  const int tid  = threadIdx.x;
  const int lane = tid & 63;
  const int task = blockIdx.x * 4 + (tid >> 6);   // 0..16383 = bl*4 + hg
  const int hg   = task & 3;                      // head group (8 heads)
  const int bl   = task >> 2;                     // b*2048 + l
  const int l    = bl & 2047;
  const int h    = hg * 8 + (lane >> 3);
  const int d0   = (lane & 7) * 8;
  const size_t base = (size_t)bl * 6144 + h * 64 + d0;

  // rope + weight for this lane's 8 dims (f32, coalesced float4 pairs)
  float r0[8], r1[8], wv[8];
  {
    const float4* p0 = (const float4*)(rope + l * 64 + d0);
    const float4* p1 = (const float4*)(rope + 131072 + l * 64 + d0);
    const float4* pw = (const float4*)(qk_w + d0);
    float4 a, b2;
    a = p0[0]; b2 = p0[1];
    r0[0]=a.x; r0[1]=a.y; r0[2]=a.z; r0[3]=a.w; r0[4]=b2.x; r0[5]=b2.y; r0[6]=b2.z; r0[7]=b2.w;
    a = p1[0]; b2 = p1[1];
    r1[0]=a.x; r1[1]=a.y; r1[2]=a.z; r1[3]=a.w; r1[4]=b2.x; r1[5]=b2.y; r1[6]=b2.z; r1[7]=b2.w;
    a = pw[0]; b2 = pw[1];
    wv[0]=a.x; wv[1]=a.y; wv[2]=a.z; wv[3]=a.w; wv[4]=b2.x; wv[5]=b2.y; wv[6]=b2.z; wv[7]=b2.w;
  }

  #pragma unroll
  for (int t = 0; t < 2; ++t) {        // t=0: q, t=1: k
    unsigned short* p = &QKV[base + (size_t)2048 * t];
    const uint4 raw = *(const uint4*)p;
    const unsigned int* u = (const unsigned int*)&raw;
    float v[8];
    #pragma unroll
    for (int j = 0; j < 4; ++j) {
      v[2*j]   = bf2f(u[j]);
      v[2*j+1] = bf2f_hi(u[j]);
    }
    float sq = v[0]*v[0] + v[1]*v[1] + v[2]*v[2] + v[3]*v[3]
             + v[4]*v[4] + v[5]*v[5] + v[6]*v[6] + v[7]*v[7];
    sq += __shfl_xor(sq, 1);
    sq += __shfl_xor(sq, 2);
    sq += __shfl_xor(sq, 4);           // sum over the 8 lanes of this row
    const float rn = rsqrtf(sq * (1.f / 64.f) + EPS_F32)
                   * ((t == 0) ? QSCALE : 1.0f);
    float vn[8];
    #pragma unroll
    for (int j = 0; j < 8; ++j) vn[j] = v[j] * (rn * wv[j]);
    unsigned int pk[4];
    #pragma unroll
    for (int j = 0; j < 4; ++j) {      // pair (2j, 2j+1): x_hat = (-x1, x0)
      const float o0 = vn[2*j]   * r0[2*j]   - vn[2*j+1] * r1[2*j];
      const float o1 = vn[2*j+1] * r0[2*j+1] + vn[2*j]   * r1[2*j+1];
      pk[j] = (unsigned int)f2bf(o0) | ((unsigned int)f2bf(o1) << 16);
    }
    *(uint4*)p = make_uint4(pk[0], pk[1], pk[2], pk[3]);
  }
}

// ---------------------------------------------------------------------------
// 6) MFMA flash attention (no-max softmax). 64q/wave, 256q/block, k-tile 64.
//    (verified R4 structure: plain two-barrier staging, no prefetch/setprio)
// ---------------------------------------------------------------------------
__global__ __launch_bounds__(256, 2) void attn_mfma_kernel(
    const unsigned short* __restrict__ QKV,  // [4096][6144] (q,k roped)
    const unsigned short* __restrict__ Vt,   // [64 bh][64 d][2048 k-perm]
    unsigned short* __restrict__ O)          // [4096][2048]
{
  __shared__ unsigned short Ks[64 * 72];
  __shared__ unsigned short Vs[64 * 72];
  __shared__ unsigned short Ps[4 * 64 * 68];
  const int tid  = threadIdx.x;
  const int lane = tid & 63;
  const int wave = tid >> 6;
  const int blk = blockIdx.x;              // 0..511
  const int bh = blk & 63;                 // blk%8 == bh%8 -> XCD-affine
  const int qt = blk >> 6;                 // 0..7
  const int b = bh >> 5, h = bh & 31;
  const int rowbase = b << 11;
  const int qbase = qt * 256 + wave * 64;  // 64 q rows per wave

  const int m16  = lane & 15;
  const int quad = lane >> 4;
  const int m32  = lane & 31;
  const int hl   = lane >> 5;

  // Q fragments (already scaled by QSCALE in rope kernel): 4 x 16-row tiles
  bf16x8 qf[4][2];
  #pragma unroll
  for (int qi = 0; qi < 4; ++qi)
    #pragma unroll
    for (int ch = 0; ch < 2; ++ch)
      qf[qi][ch] = *(const bf16x8*)&QKV[(size_t)(rowbase + qbase + qi * 16 + m16) * 6144
                                        + h * 64 + ch * 32 + quad * 8];

  const int sr = tid >> 2;            // staging row 0..63
  const int sc = (tid & 3) * 16;      // staging col (shorts)
  const unsigned short* Kg = QKV + (size_t)(rowbase + sr) * 6144 + 2048 + h * 64 + sc;
  const unsigned short* Vg = Vt + (size_t)(bh * 64 + sr) * 2048 + sc;

  f32x16 accO[2][2] = {};                 // [q-subtile 32][d-tile 32]
  float part[4][4] = {};                  // per-16-row-tile row sums
  unsigned short* Pw = &Ps[(wave * 64) * 68];

  for (int kt = 0; kt < 32; ++kt) {
    __syncthreads();
    {
      const uint4* kp = (const uint4*)(Kg + (size_t)kt * 64 * 6144);
      const uint4* vp = (const uint4*)(Vg + kt * 64);
      uint4 k0 = kp[0], k1 = kp[1];
      uint4 v0 = vp[0], v1 = vp[1];
      *(uint4*)&Ks[sr * 72 + sc]     = k0;
      *(uint4*)&Ks[sr * 72 + sc + 8] = k1;
      *(uint4*)&Vs[sr * 72 + sc]     = v0;
      *(uint4*)&Vs[sr * 72 + sc + 8] = v1;
    }
    __syncthreads();

    // S (16x16x32) -> exp2 -> pack P (key perm p = c*4 + kj)
    unsigned int pk[4][4][2];
    #pragma unroll
    for (int kj = 0; kj < 4; ++kj) {
      bf16x8 kf0 = *(const bf16x8*)&Ks[(kj * 16 + m16) * 72 + quad * 8];
      bf16x8 kf1 = *(const bf16x8*)&Ks[(kj * 16 + m16) * 72 + 32 + quad * 8];
      #pragma unroll
      for (int qi = 0; qi < 4; ++qi) {
        f32x4 acc = {};
        acc = __builtin_amdgcn_mfma_f32_16x16x32_bf16(qf[qi][0], kf0, acc, 0, 0, 0);
        acc = __builtin_amdgcn_mfma_f32_16x16x32_bf16(qf[qi][1], kf1, acc, 0, 0, 0);
        #pragma unroll
        for (int r = 0; r < 4; ++r) {
          float p = EXP2F(acc[r]);
          part[qi][r] += p;
          unsigned int pb = f2bf_rn_u(p);
          if (kj == 0)      pk[qi][r][0]  = pb >> 16;
          else if (kj == 1) pk[qi][r][0] |= pb & 0xffff0000u;
          else if (kj == 2) pk[qi][r][1]  = pb >> 16;
          else              pk[qi][r][1] |= pb & 0xffff0000u;
        }
      }
    }
    #pragma unroll
    for (int qi = 0; qi < 4; ++qi)
      #pragma unroll
      for (int r = 0; r < 4; ++r)
        *(uint2*)&Pw[(qi * 16 + quad * 4 + r) * 68 + m16 * 4] =
            make_uint2(pk[qi][r][0], pk[qi][r][1]);
    // wave-private P region: RAW covered by lgkmcnt, no barrier

    // PV (32x32x16): accO[qs][dt], vb reused across qs
    #pragma unroll
    for (int ch = 0; ch < 4; ++ch) {
      bf16x8 pa0 = *(const bf16x8*)&Pw[m32 * 68 + ch * 16 + hl * 8];
      bf16x8 pa1 = *(const bf16x8*)&Pw[(32 + m32) * 68 + ch * 16 + hl * 8];
      bf16x8 vb0 = *(const bf16x8*)&Vs[m32 * 72 + ch * 16 + hl * 8];
      bf16x8 vb1 = *(const bf16x8*)&Vs[(32 + m32) * 72 + ch * 16 + hl * 8];
      accO[0][0] = __builtin_amdgcn_mfma_f32_32x32x16_bf16(pa0, vb0, accO[0][0], 0, 0, 0);
      accO[0][1] = __builtin_amdgcn_mfma_f32_32x32x16_bf16(pa0, vb1, accO[0][1], 0, 0, 0);
      accO[1][0] = __builtin_amdgcn_mfma_f32_32x32x16_bf16(pa1, vb0, accO[1][0], 0, 0, 0);
      accO[1][1] = __builtin_amdgcn_mfma_f32_32x32x16_bf16(pa1, vb1, accO[1][1], 0, 0, 0);
    }
  }

  // reduce row sums over the 16 n-lanes
  #pragma unroll
  for (int qi = 0; qi < 4; ++qi)
    #pragma unroll
    for (int r = 0; r < 4; ++r)
      #pragma unroll
      for (int off = 1; off < 16; off <<= 1)
        part[qi][r] += __shfl_xor(part[qi][r], off);

  // epilogue: per 32-row q-subtile, gather row sum, divide, store
  #pragma unroll
  for (int qs = 0; qs < 2; ++qs) {
    #pragma unroll
    for (int reg = 0; reg < 16; ++reg) {
      const int r = reg & 3;
      const int s = reg >> 2;
      const int qsrc = ((2 * s + hl) & 3) * 16 + m16;
      const float rs = __shfl(part[qs * 2 + (reg >> 3)][r], qsrc);
      const float inv = RCPF(rs);
      const int rho = r + 8 * s + 4 * hl;      // row in 32x32 C layout
      const size_t base = (size_t)(rowbase + qbase + qs * 32 + rho) * 2048 + h * 64;
      O[base + m32]      = f2bf(accO[qs][0][reg] * inv);
      O[base + 32 + m32] = f2bf(accO[qs][1][reg] * inv);
    }
  }
}

// ---------------------------------------------------------------------------
// launch
// ---------------------------------------------------------------------------
extern "C" void kernel_launch(void* const* d_in, const int* in_sizes, int n_in,
                              void* d_out, int out_size, void* d_ws, size_t ws_size,
                              hipStream_t stream) {
  (void)in_sizes; (void)n_in; (void)out_size; (void)ws_size;
  const float* x     = (const float*)d_in[0];
  const float* cond  = (const float*)d_in[1];
  const float* rope  = (const float*)d_in[2];
  const float* w_ada = (const float*)d_in[3];
  const float* w_qkv = (const float*)d_in[4];
  const float* w_out = (const float*)d_in[5];
  const float* qk_w  = (const float*)d_in[6];
  float* out = (float*)d_out;

  char* ws = (char*)d_ws;
  float*          ss   = (float*)ws;                       // 32 KB
  unsigned short* H    = (unsigned short*)(ws + 32768);    // 16 MB, reused as O
  unsigned short* Wq   = H + 8388608;                      // 24 MB
  unsigned short* Wo   = Wq + 12582912;                    // 8 MB  (contiguous after Wq)
  unsigned short* QKV  = Wo + 4194304;                     // 48 MB (q,k used)
  unsigned short* Vt_g = QKV + 25165824;                   // 16 MB

  ada_gemm_kernel<<<2048, 256, 0, stream>>>(cond, w_ada, ss);
  ada_rms_kernel<<<4096, 256, 0, stream>>>(x, ss, H);
  cast2_kernel<<<16384, 256, 0, stream>>>(w_qkv, w_out, Wq);
  // qkv = H @ w_qkv^T ; q,k -> QKV bf16, v -> Vt_g (transposed + k-permuted)
  gemm_qkv_4p<<<768, 512, 0, stream>>>(H, Wq, QKV, Vt_g);
  qk_rope_kernel<<<4096, 256, 0, stream>>>(QKV, rope, qk_w);
  attn_mfma_kernel<<<512, 256, 0, stream>>>(QKV, Vt_g, H);
  gemm_out_4p<<<256, 512, 0, stream>>>(H, Wo, out);
}

// Round 10
// 432.717 us; speedup vs baseline: 1.1066x; 1.0255x over previous
//
#include <hip/hip_runtime.h>

// ---------------------------------------------------------------------------
// Attention_17703855194398: AdaRMSNorm -> QKV -> per-head RMS+RoPE -> SDPA -> out
// B=2, L=2048, D=2048, NH=32, HD=64, DC=2048
// R13: recombination of best measured variants.
//  - QKV GEMM: R1-verified 256x256 8-phase (plain epilogue; 4p/768 was 128.7us
//    vs 8p <=122 — tile AI + schedule depth beat grid balance).
//  - rope: separate R8-vectorized kernel (~9us; fusing cost ~16us in R11).
//  - out-proj: 256x128 4-phase, grid 256 (verified R11/R12).
//  - attn: verified R4 structure (4 structural alternatives all regressed).
// ---------------------------------------------------------------------------

typedef __bf16 bf16x8 __attribute__((ext_vector_type(8)));
typedef float  f32x4  __attribute__((ext_vector_type(4)));
typedef float  f32x16 __attribute__((ext_vector_type(16)));

#define EPS_F32 1.1920929e-07f
// q prescale: (1/sqrt(64)) * log2(e)  -> scores land in exp2 domain
#define QSCALE 0.18033688011112042f

#if defined(__has_builtin)
#  if __has_builtin(__builtin_amdgcn_exp2f)
#    define EXP2F(x) __builtin_amdgcn_exp2f(x)
#  else
#    define EXP2F(x) __expf((x) * 0.6931471805599453f)
#  endif
#  if __has_builtin(__builtin_amdgcn_rcpf)
#    define RCPF(x) __builtin_amdgcn_rcpf(x)
#  else
#    define RCPF(x) (1.0f / (x))
#  endif
#else
#  define EXP2F(x) __expf((x) * 0.6931471805599453f)
#  define RCPF(x) (1.0f / (x))
#endif

__device__ __forceinline__ float bf2f(unsigned int u16) {
  union { unsigned int i; float f; } v; v.i = (u16 & 0xffffu) << 16; return v.f;
}
__device__ __forceinline__ float bf2f_hi(unsigned int u32) {
  union { unsigned int i; float f; } v; v.i = u32 & 0xffff0000u; return v.f;
}
__device__ __forceinline__ unsigned short f2bf(float f) {
  union { float f; unsigned int i; } v; v.f = f;
  unsigned int r = v.i + 0x7fffu + ((v.i >> 16) & 1u);  // RNE
  return (unsigned short)(r >> 16);
}
// round-to-nearest (ties away) bf16 bits, cheap: 2 ops
__device__ __forceinline__ unsigned int f2bf_rn_u(float f) {
  union { float f; unsigned int i; } v; v.f = f;
  return v.i + 0x8000u;   // caller takes >>16 or &0xffff0000
}

// async global->LDS, 16B per lane (wave-uniform base + lane*16)
__device__ __forceinline__ void gload16(const void* g, void* l) {
  __builtin_amdgcn_global_load_lds(
      (const __attribute__((address_space(1))) unsigned int*)(unsigned long long)g,
      (__attribute__((address_space(3))) unsigned int*)(unsigned int)(unsigned long long)l,
      16, 0, 0);
}

// ---------------------------------------------------------------------------
// 1) ada GEMM: ss[b,j] = sum_k cond[b,k] * w_ada[j,k]
// ---------------------------------------------------------------------------
__global__ __launch_bounds__(256) void ada_gemm_kernel(
    const float* __restrict__ cond, const float* __restrict__ w_ada,
    float* __restrict__ ss)
{
  const int lane = threadIdx.x & 63;
  const int gw = blockIdx.x * 4 + (threadIdx.x >> 6);
  const int b = gw >> 12;
  const int j = gw & 4095;
  const float4* wr = (const float4*)(w_ada + j * 2048);
  const float4* cr = (const float4*)(cond + b * 2048);
  float acc = 0.f;
  #pragma unroll
  for (int k4 = 0; k4 < 8; ++k4) {
    float4 w = wr[lane + k4 * 64];
    float4 c = cr[lane + k4 * 64];
    acc += w.x * c.x + w.y * c.y + w.z * c.z + w.w * c.w;
  }
  #pragma unroll
  for (int off = 1; off < 64; off <<= 1) acc += __shfl_xor(acc, off);
  if (lane == 0) ss[b * 4096 + j] = acc;
}

// ---------------------------------------------------------------------------
// 2) AdaRMSNorm: h = rms_norm(x)*(1+scale) + shift, write bf16
// ---------------------------------------------------------------------------
__global__ __launch_bounds__(256) void ada_rms_kernel(
    const float* __restrict__ x, const float* __restrict__ ss,
    unsigned short* __restrict__ H)
{
  const int row = blockIdx.x;
  const int b = row >> 11;
  const int tid = threadIdx.x;
  const int lane = tid & 63, wave = tid >> 6;
  const float* xr = x + (size_t)row * 2048;
  float4 v0 = ((const float4*)xr)[tid * 2];
  float4 v1 = ((const float4*)xr)[tid * 2 + 1];
  float ssq = v0.x*v0.x + v0.y*v0.y + v0.z*v0.z + v0.w*v0.w
            + v1.x*v1.x + v1.y*v1.y + v1.z*v1.z + v1.w*v1.w;
  #pragma unroll
  for (int off = 1; off < 64; off <<= 1) ssq += __shfl_xor(ssq, off);
  __shared__ float red[4];
  if (lane == 0) red[wave] = ssq;
  __syncthreads();
  const float tot = red[0] + red[1] + red[2] + red[3];
  const float r = rsqrtf(tot * (1.f / 2048.f) + EPS_F32);
  const int c0 = tid * 8;
  const float* sh = ss + b * 4096;
  float xv[8] = {v0.x, v0.y, v0.z, v0.w, v1.x, v1.y, v1.z, v1.w};
  unsigned int pk[4];
  #pragma unroll
  for (int p = 0; p < 4; ++p) {
    const int c = c0 + p * 2;
    float h0 = xv[p*2+0] * r * (1.f + sh[2048 + c])     + sh[c];
    float h1 = xv[p*2+1] * r * (1.f + sh[2048 + c + 1]) + sh[c + 1];
    pk[p] = (unsigned int)f2bf(h0) | ((unsigned int)f2bf(h1) << 16);
  }
  *(uint4*)&H[(size_t)row * 2048 + c0] = make_uint4(pk[0], pk[1], pk[2], pk[3]);
}

// ---------------------------------------------------------------------------
// 3) fp32 -> bf16 weight cast, both weights in one launch.
//    dst is contiguous: [w_qkv bf16 : 12582912][w_out bf16 : 4194304]
// ---------------------------------------------------------------------------
__global__ __launch_bounds__(256) void cast2_kernel(
    const float* __restrict__ a,   // w_qkv, 3145728 float4
    const float* __restrict__ b,   // w_out, 1048576 float4
    unsigned short* __restrict__ dst)
{
  const int i = blockIdx.x * 256 + threadIdx.x;   // 0..4194303
  float4 v = (i < 3145728) ? ((const float4*)a)[i]
                           : ((const float4*)b)[i - 3145728];
  unsigned int p0 = (unsigned int)f2bf(v.x) | ((unsigned int)f2bf(v.y) << 16);
  unsigned int p1 = (unsigned int)f2bf(v.z) | ((unsigned int)f2bf(v.w) << 16);
  *(uint2*)&dst[(size_t)i * 4] = make_uint2(p0, p1);
}

// ---------------------------------------------------------------------------
// 4a) QKV GEMM: 256x256 tile, BK=64, 8-phase schedule (8 waves = 2M x 4N).
//    M=4096, N=6144, K=2048 hardcoded. A=[M,K] bf16, Bw=[N,K] bf16.
//    LDS: [buf][khalf][row][32] for A and B (128 KiB total), k-octet slot
//    XOR-swizzle applied on the GLOBAL source address and the ds_read addr.
//    vmcnt(4) at phases 2/4/6/8 only — loads stay in flight across barriers.
//    Epilogue: q/k (bn<4096) plain bf16; v (bn>=4096) -> Vt scatter.
//    (R1-verified kernel, unmodified.)
// ---------------------------------------------------------------------------
__global__ __launch_bounds__(512, 2) void gemm_qkv_8p(
    const unsigned short* __restrict__ A,
    const unsigned short* __restrict__ Bw,
    unsigned short* __restrict__ C,
    unsigned short* __restrict__ vt)
{
  __shared__ unsigned short As[2][2][8192];   // [buf][khalf][256 rows * 32 k]
  __shared__ unsigned short Bs[2][2][8192];

  const int tid  = threadIdx.x;
  const int lane = tid & 63;
  const int wave = tid >> 6;              // 0..7
  const int wrow = (wave >> 2) * 128;     // 0 / 128
  const int wcol = (wave & 3) * 64;       // 0 / 64 / 128 / 192

  // bijective XCD chunk swizzle (384 % 8 == 0); chunks are bx-major so each
  // XCD keeps 3 B-panels (3 MB) hot in its L2 while streaming A via L3.
  const int swz = (blockIdx.x & 7) * 48 + (blockIdx.x >> 3);
  const int bx = swz >> 4;                // 0..23  (N tiles)
  const int by = swz & 15;                // 0..15  (M tiles)
  const int bm = by * 256;
  const int bn = bx * 256;

  const int fr = lane & 15;
  const int q_ = lane >> 4;
  const int laneoff = fr * 32 + ((q_ ^ ((fr >> 1) & 3)) << 3);

  const int rA  = wave * 32 + (lane >> 2);            // j=0 row (j=1: +16)
  const int kk  = (lane & 3) ^ ((lane >> 3) & 3);     // inverse-swizzled k-octet
  const unsigned short* Ag0 = A  + (size_t)(bm + rA) * 2048 + kk * 8;
  const unsigned short* Ag1 = Ag0 + (size_t)16 * 2048;
  const unsigned short* Bg0 = Bw + (size_t)(bn + rA) * 2048 + kk * 8;
  const unsigned short* Bg1 = Bg0 + (size_t)16 * 2048;
  const int ldso = rA * 32 + (lane & 3) * 8;          // linear LDS dest (j=1: +512)

  f32x4 acc[8][4] = {};
  bf16x8 fA[4], fB[4];

#define STAGE_A(SB, SKH, KT) do { \
    gload16(Ag0 + (KT) * 64 + (SKH) * 32, &As[SB][SKH][ldso]); \
    gload16(Ag1 + (KT) * 64 + (SKH) * 32, &As[SB][SKH][ldso + 512]); } while (0)
#define STAGE_B(SB, SKH, KT) do { \
    gload16(Bg0 + (KT) * 64 + (SKH) * 32, &Bs[SB][SKH][ldso]); \
    gload16(Bg1 + (KT) * 64 + (SKH) * 32, &Bs[SB][SKH][ldso + 512]); } while (0)
#define VMW(N) asm volatile("s_waitcnt vmcnt(" #N ")" ::: "memory")
#define LDB(BUF, KH) do { const unsigned short* p_ = &Bs[BUF][KH][wcol * 32 + laneoff]; \
    fB[0] = *(const bf16x8*)&p_[0];    fB[1] = *(const bf16x8*)&p_[512]; \
    fB[2] = *(const bf16x8*)&p_[1024]; fB[3] = *(const bf16x8*)&p_[1536]; } while (0)
#define LDA(BUF, KH, MH) do { const unsigned short* p_ = &As[BUF][KH][(wrow + (MH) * 64) * 32 + laneoff]; \
    fA[0] = *(const bf16x8*)&p_[0];    fA[1] = *(const bf16x8*)&p_[512]; \
    fA[2] = *(const bf16x8*)&p_[1024]; fA[3] = *(const bf16x8*)&p_[1536]; } while (0)
#define MFMA16(MH) do { \
    _Pragma("unroll") \
    for (int f_ = 0; f_ < 4; ++f_) { \
      _Pragma("unroll") \
      for (int n_ = 0; n_ < 4; ++n_) \
        acc[(MH) * 4 + f_][n_] = __builtin_amdgcn_mfma_f32_16x16x32_bf16( \
            fA[f_], fB[n_], acc[(MH) * 4 + f_][n_], 0, 0, 0); \
    } } while (0)
#define PH_MID() do { __builtin_amdgcn_s_barrier(); \
    asm volatile("s_waitcnt lgkmcnt(0)"); \
    __builtin_amdgcn_s_setprio(1); } while (0)
#define PH_END() do { __builtin_amdgcn_s_setprio(0); \
    __builtin_amdgcn_s_barrier(); } while (0)

  // prologue: stage K-tile 0 into buf0 (order Ak0, Bk0, Ak1, Bk1)
  STAGE_A(0, 0, 0); STAGE_B(0, 0, 0); STAGE_A(0, 1, 0); STAGE_B(0, 1, 0);
  VMW(4);                      // Ak0+Bk0 landed; Ak1+Bk1 still in flight
  __builtin_amdgcn_s_barrier();

  for (int it = 0; it < 16; ++it) {
    const int t1 = 2 * it + 1;
    const int t2 = 2 * it + 2;
    const bool pf = (it < 15);

    // ---- K-tile 2it (buf0); stage K-tile 2it+1 -> buf1 ----
    LDB(0, 0); LDA(0, 0, 0);
    STAGE_A(1, 0, t1);
    PH_MID(); MFMA16(0); PH_END();
    LDA(0, 0, 1);
    STAGE_B(1, 0, t1);
    VMW(4);                    // retire prev P7/P8 (buf0 Ak1,Bk1) for P3
    PH_MID(); MFMA16(1); PH_END();
    LDB(0, 1); LDA(0, 1, 0);
    STAGE_A(1, 1, t1);
    PH_MID(); MFMA16(0); PH_END();
    LDA(0, 1, 1);
    STAGE_B(1, 1, t1);
    VMW(4);                    // retire P1/P2 (buf1 Ak0,Bk0) for P5
    PH_MID(); MFMA16(1); PH_END();

    // ---- K-tile 2it+1 (buf1); stage K-tile 2it+2 -> buf0 ----
    LDB(1, 0); LDA(1, 0, 0);
    if (pf) STAGE_A(0, 0, t2);
    PH_MID(); MFMA16(0); PH_END();
    LDA(1, 0, 1);
    if (pf) { STAGE_B(0, 0, t2); VMW(4); }  // retire P3/P4 (buf1 Ak1,Bk1)
    else    { VMW(0); }                     // last iter: drain P3/P4
    PH_MID(); MFMA16(1); PH_END();
    LDB(1, 1); LDA(1, 1, 0);
    if (pf) STAGE_A(0, 1, t2);
    PH_MID(); MFMA16(0); PH_END();
    LDA(1, 1, 1);
    if (pf) STAGE_B(0, 1, t2);
    VMW(4);                    // retire P5/P6 (buf0 Ak0,Bk0) for next P1
    PH_MID(); MFMA16(1); PH_END();
  }

#undef STAGE_A
#undef STAGE_B
#undef VMW
#undef LDB
#undef LDA
#undef MFMA16
#undef PH_MID
#undef PH_END

  // epilogue: per-wave 128x64 C block. bn is a multiple of 256 so each block
  // is purely q/k (linear) or purely v (Vt scatter).
  const int cr = (lane >> 4) * 4;
  const int cc = lane & 15;
  if (bn >= 4096) {
    #pragma unroll
    for (int mf = 0; mf < 8; ++mf)
      #pragma unroll
      for (int nf = 0; nf < 4; ++nf)
        #pragma unroll
        for (int r = 0; r < 4; ++r) {
          const int m  = bm + wrow + mf * 16 + cr + r;
          const int dg = bn + wcol + nf * 16 + cc - 4096;
          const int l  = m & 2047;
          const size_t dst = ((size_t)((m >> 11) * 32 + (dg >> 6)) * 64 + (dg & 63)) * 2048
                           + (l >> 6) * 64 + (l & 15) * 4 + ((l >> 4) & 3);
          vt[dst] = f2bf(acc[mf][nf][r]);
        }
  } else {
    #pragma unroll
    for (int mf = 0; mf < 8; ++mf)
      #pragma unroll
      for (int nf = 0; nf < 4; ++nf)
        #pragma unroll
        for (int r = 0; r < 4; ++r) {
          const int row = bm + wrow + mf * 16 + cr + r;
          const int col = bn + wcol + nf * 16 + cc;
          C[(size_t)row * 6144 + col] = f2bf(acc[mf][nf][r]);
        }
  }
}

// ---------------------------------------------------------------------------
// 4b) out-projection GEMM: 256x128 tile, BK=64, 4-phase schedule,
//    512 threads (8 waves = 4M x 2N). grid 256 = exactly 1 block/CU.
//    A = attn O [4096][2048] bf16, Bw = w_out [2048][2048] bf16, C f32.
// ---------------------------------------------------------------------------
__global__ __launch_bounds__(512, 1) void gemm_out_4p(
    const unsigned short* __restrict__ A,
    const unsigned short* __restrict__ Bw,
    float* __restrict__ C)
{
  __shared__ unsigned short As[2][2][8192];   // [buf][khalf][256 rows * 32 k]
  __shared__ unsigned short Bs[2][2][4096];   // [buf][khalf][128 rows * 32 k]

  const int tid  = threadIdx.x;
  const int lane = tid & 63;
  const int wave = tid >> 6;              // 0..7
  const int wrow = (wave >> 1) * 64;      // 0/64/128/192
  const int wcol = (wave & 1) * 64;       // 0/64

  // bijective XCD chunk swizzle (256 % 8 == 0, 32 blocks per XCD)
  const int swz = (blockIdx.x & 7) * 32 + (blockIdx.x >> 3);
  const int bx = swz >> 4;                // 0..15 (N tiles of 128)
  const int by = swz & 15;                // 0..15 (M tiles of 256)
  const int bm = by * 256;
  const int bn = bx * 128;

  const int fr = lane & 15;
  const int q_ = lane >> 4;
  const int laneoff = fr * 32 + ((q_ ^ ((fr >> 1) & 3)) << 3);

  const int rA = wave * 32 + (lane >> 2);             // A rows (2nd load: +16)
  const int rB = wave * 16 + (lane >> 2);             // B rows
  const int kk = (lane & 3) ^ ((lane >> 3) & 3);      // inverse-swizzled k-octet
  const unsigned short* Ag0 = A  + (size_t)(bm + rA) * 2048 + kk * 8;
  const unsigned short* Ag1 = Ag0 + (size_t)16 * 2048;
  const unsigned short* Bg0 = Bw + (size_t)(bn + rB) * 2048 + kk * 8;
  const int ldsoA = rA * 32 + (lane & 3) * 8;
  const int ldsoB = rB * 32 + (lane & 3) * 8;

  f32x4 acc[4][4] = {};
  bf16x8 fA[4], fB[4];

#define STAGE_A4(SB, SKH, KT) do { \
    gload16(Ag0 + (KT) * 64 + (SKH) * 32, &As[SB][SKH][ldsoA]); \
    gload16(Ag1 + (KT) * 64 + (SKH) * 32, &As[SB][SKH][ldsoA + 512]); } while (0)
#define STAGE_B4(SB, SKH, KT) \
    gload16(Bg0 + (KT) * 64 + (SKH) * 32, &Bs[SB][SKH][ldsoB])
#define VMW(N) asm volatile("s_waitcnt vmcnt(" #N ")" ::: "memory")
#define LDB4(BUF, KH) do { const unsigned short* p_ = &Bs[BUF][KH][wcol * 32 + laneoff]; \
    fB[0] = *(const bf16x8*)&p_[0];    fB[1] = *(const bf16x8*)&p_[512]; \
    fB[2] = *(const bf16x8*)&p_[1024]; fB[3] = *(const bf16x8*)&p_[1536]; } while (0)
#define LDA4(BUF, KH) do { const unsigned short* p_ = &As[BUF][KH][wrow * 32 + laneoff]; \
    fA[0] = *(const bf16x8*)&p_[0];    fA[1] = *(const bf16x8*)&p_[512]; \
    fA[2] = *(const bf16x8*)&p_[1024]; fA[3] = *(const bf16x8*)&p_[1536]; } while (0)
#define MFMA16_4() do { \
    _Pragma("unroll") \
    for (int f_ = 0; f_ < 4; ++f_) { \
      _Pragma("unroll") \
      for (int n_ = 0; n_ < 4; ++n_) \
        acc[f_][n_] = __builtin_amdgcn_mfma_f32_16x16x32_bf16( \
            fA[f_], fB[n_], acc[f_][n_], 0, 0, 0); \
    } } while (0)
#define PH_MID() do { __builtin_amdgcn_s_barrier(); \
    asm volatile("s_waitcnt lgkmcnt(0)"); \
    __builtin_amdgcn_s_setprio(1); } while (0)
#define PH_END() do { __builtin_amdgcn_s_setprio(0); \
    __builtin_amdgcn_s_barrier(); } while (0)

  // prologue: stage K-tile 0 (k0 batch: A 2 loads + B 1; then k1 batch)
  STAGE_A4(0, 0, 0); STAGE_B4(0, 0, 0);
  STAGE_A4(0, 1, 0); STAGE_B4(0, 1, 0);
  VMW(3);                      // k0 batch landed; k1 batch in flight
  __builtin_amdgcn_s_barrier();

  for (int it = 0; it < 16; ++it) {
    const int t1 = 2 * it + 1;
    const int t2 = 2 * it + 2;
    const bool pf = (it < 15);

    // ---- K-tile 2it (buf0); stage K-tile 2it+1 -> buf1 ----
    LDB4(0, 0); LDA4(0, 0);
    STAGE_A4(1, 0, t1); STAGE_B4(1, 0, t1);
    VMW(3);                    // retire prev tile's k1 batch (read next phase)
    PH_MID(); MFMA16_4(); PH_END();
    LDB4(0, 1); LDA4(0, 1);
    STAGE_A4(1, 1, t1); STAGE_B4(1, 1, t1);
    VMW(3);                    // retire buf1-k0 batch
    PH_MID(); MFMA16_4(); PH_END();

    // ---- K-tile 2it+1 (buf1); stage K-tile 2it+2 -> buf0 ----
    LDB4(1, 0); LDA4(1, 0);
    if (pf) { STAGE_A4(0, 0, t2); STAGE_B4(0, 0, t2); VMW(3); }
    else    { VMW(0); }
    PH_MID(); MFMA16_4(); PH_END();
    LDB4(1, 1); LDA4(1, 1);
    if (pf) { STAGE_A4(0, 1, t2); STAGE_B4(0, 1, t2); VMW(3); }
    else    { VMW(0); }
    PH_MID(); MFMA16_4(); PH_END();
  }

#undef STAGE_A4
#undef STAGE_B4
#undef VMW
#undef LDB4
#undef LDA4
#undef MFMA16_4
#undef PH_MID
#undef PH_END

  // epilogue: f32 C write, per wave 64x64 block
  const int cr = (lane >> 4) * 4;
  const int cc = lane & 15;
  #pragma unroll
  for (int f = 0; f < 4; ++f)
    #pragma unroll
    for (int n = 0; n < 4; ++n)
      #pragma unroll
      for (int r = 0; r < 4; ++r) {
        const int row = bm + wrow + f * 16 + cr + r;
        const int col = bn + wcol + n * 16 + cc;
        C[(size_t)row * 2048 + col] = acc[f][n][r];
      }
}

// ---------------------------------------------------------------------------
// 5) per-head RMSNorm(qk_w) + RoPE on q,k in place; q scaled by QSCALE.
//    Vectorized (R8): bf16x8 per lane, rotation lane-local, 3 shuffles per
//    8 elements, float4 table loads.
// ---------------------------------------------------------------------------
__global__ __launch_bounds__(256) void qk_rope_kernel(
    unsigned short* __restrict__ QKV, const float* __restrict__ rope,
    const float* __restrict__ qk_w)
{
  const int tid  = threadIdx.x;
  const int lane = tid & 63;
  const int task = blockIdx.x * 4 + (tid >> 6);   // 0..16383 = bl*4 + hg
  const int hg   = task & 3;                      // head group (8 heads)
  const int bl   = task >> 2;                     // b*2048 + l
  const int l    = bl & 2047;
  const int h    = hg * 8 + (lane >> 3);
  const int d0   = (lane & 7) * 8;
  const size_t base = (size_t)bl * 6144 + h * 64 + d0;

  // rope + weight for this lane's 8 dims (f32, coalesced float4 pairs)
  float r0[8], r1[8], wv[8];
  {
    const float4* p0 = (const float4*)(rope + l * 64 + d0);
    const float4* p1 = (const float4*)(rope + 131072 + l * 64 + d0);
    const float4* pw = (const float4*)(qk_w + d0);
    float4 a, b2;
    a = p0[0]; b2 = p0[1];
    r0[0]=a.x; r0[1]=a.y; r0[2]=a.z; r0[3]=a.w; r0[4]=b2.x; r0[5]=b2.y; r0[6]=b2.z; r0[7]=b2.w;
    a = p1[0]; b2 = p1[1];
    r1[0]=a.x; r1[1]=a.y; r1[2]=a.z; r1[3]=a.w; r1[4]=b2.x; r1[5]=b2.y; r1[6]=b2.z; r1[7]=b2.w;
    a = pw[0]; b2 = pw[1];
    wv[0]=a.x; wv[1]=a.y; wv[2]=a.z; wv[3]=a.w; wv[4]=b2.x; wv[5]=b2.y; wv[6]=b2.z; wv[7]=b2.w;
  }

  #pragma unroll
  for (int t = 0; t < 2; ++t) {        // t=0: q, t=1: k
    unsigned short* p = &QKV[base + (size_t)2048 * t];
    const uint4 raw = *(const uint4*)p;
    const unsigned int* u = (const unsigned int*)&raw;
    float v[8];
    #pragma unroll
    for (int j = 0; j < 4; ++j) {
      v[2*j]   = bf2f(u[j]);
      v[2*j+1] = bf2f_hi(u[j]);
    }
    float sq = v[0]*v[0] + v[1]*v[1] + v[2]*v[2] + v[3]*v[3]
             + v[4]*v[4] + v[5]*v[5] + v[6]*v[6] + v[7]*v[7];
    sq += __shfl_xor(sq, 1);
    sq += __shfl_xor(sq, 2);
    sq += __shfl_xor(sq, 4);           // sum over the 8 lanes of this row
    const float rn = rsqrtf(sq * (1.f / 64.f) + EPS_F32)
                   * ((t == 0) ? QSCALE : 1.0f);
    float vn[8];
    #pragma unroll
    for (int j = 0; j < 8; ++j) vn[j] = v[j] * (rn * wv[j]);
    unsigned int pk[4];
    #pragma unroll
    for (int j = 0; j < 4; ++j) {      // pair (2j, 2j+1): x_hat = (-x1, x0)
      const float o0 = vn[2*j]   * r0[2*j]   - vn[2*j+1] * r1[2*j];
      const float o1 = vn[2*j+1] * r0[2*j+1] + vn[2*j]   * r1[2*j+1];
      pk[j] = (unsigned int)f2bf(o0) | ((unsigned int)f2bf(o1) << 16);
    }
    *(uint4*)p = make_uint4(pk[0], pk[1], pk[2], pk[3]);
  }
}

// ---------------------------------------------------------------------------
// 6) MFMA flash attention (no-max softmax). 64q/wave, 256q/block, k-tile 64.
//    (verified R4 structure: plain two-barrier staging, no prefetch/setprio)
// ---------------------------------------------------------------------------
__global__ __launch_bounds__(256, 2) void attn_mfma_kernel(
    const unsigned short* __restrict__ QKV,  // [4096][6144] (q,k roped)
    const unsigned short* __restrict__ Vt,   // [64 bh][64 d][2048 k-perm]
    unsigned short* __restrict__ O)          // [4096][2048]
{
  __shared__ unsigned short Ks[64 * 72];
  __shared__ unsigned short Vs[64 * 72];
  __shared__ unsigned short Ps[4 * 64 * 68];
  const int tid  = threadIdx.x;
  const int lane = tid & 63;
  const int wave = tid >> 6;
  const int blk = blockIdx.x;              // 0..511
  const int bh = blk & 63;                 // blk%8 == bh%8 -> XCD-affine
  const int qt = blk >> 6;                 // 0..7
  const int b = bh >> 5, h = bh & 31;
  const int rowbase = b << 11;
  const int qbase = qt * 256 + wave * 64;  // 64 q rows per wave

  const int m16  = lane & 15;
  const int quad = lane >> 4;
  const int m32  = lane & 31;
  const int hl   = lane >> 5;

  // Q fragments (already scaled by QSCALE in rope kernel): 4 x 16-row tiles
  bf16x8 qf[4][2];
  #pragma unroll
  for (int qi = 0; qi < 4; ++qi)
    #pragma unroll
    for (int ch = 0; ch < 2; ++ch)
      qf[qi][ch] = *(const bf16x8*)&QKV[(size_t)(rowbase + qbase + qi * 16 + m16) * 6144
                                        + h * 64 + ch * 32 + quad * 8];

  const int sr = tid >> 2;            // staging row 0..63
  const int sc = (tid & 3) * 16;      // staging col (shorts)
  const unsigned short* Kg = QKV + (size_t)(rowbase + sr) * 6144 + 2048 + h * 64 + sc;
  const unsigned short* Vg = Vt + (size_t)(bh * 64 + sr) * 2048 + sc;

  f32x16 accO[2][2] = {};                 // [q-subtile 32][d-tile 32]
  float part[4][4] = {};                  // per-16-row-tile row sums
  unsigned short* Pw = &Ps[(wave * 64) * 68];

  for (int kt = 0; kt < 32; ++kt) {
    __syncthreads();
    {
      const uint4* kp = (const uint4*)(Kg + (size_t)kt * 64 * 6144);
      const uint4* vp = (const uint4*)(Vg + kt * 64);
      uint4 k0 = kp[0], k1 = kp[1];
      uint4 v0 = vp[0], v1 = vp[1];
      *(uint4*)&Ks[sr * 72 + sc]     = k0;
      *(uint4*)&Ks[sr * 72 + sc + 8] = k1;
      *(uint4*)&Vs[sr * 72 + sc]     = v0;
      *(uint4*)&Vs[sr * 72 + sc + 8] = v1;
    }
    __syncthreads();

    // S (16x16x32) -> exp2 -> pack P (key perm p = c*4 + kj)
    unsigned int pk[4][4][2];
    #pragma unroll
    for (int kj = 0; kj < 4; ++kj) {
      bf16x8 kf0 = *(const bf16x8*)&Ks[(kj * 16 + m16) * 72 + quad * 8];
      bf16x8 kf1 = *(const bf16x8*)&Ks[(kj * 16 + m16) * 72 + 32 + quad * 8];
      #pragma unroll
      for (int qi = 0; qi < 4; ++qi) {
        f32x4 acc = {};
        acc = __builtin_amdgcn_mfma_f32_16x16x32_bf16(qf[qi][0], kf0, acc, 0, 0, 0);
        acc = __builtin_amdgcn_mfma_f32_16x16x32_bf16(qf[qi][1], kf1, acc, 0, 0, 0);
        #pragma unroll
        for (int r = 0; r < 4; ++r) {
          float p = EXP2F(acc[r]);
          part[qi][r] += p;
          unsigned int pb = f2bf_rn_u(p);
          if (kj == 0)      pk[qi][r][0]  = pb >> 16;
          else if (kj == 1) pk[qi][r][0] |= pb & 0xffff0000u;
          else if (kj == 2) pk[qi][r][1]  = pb >> 16;
          else              pk[qi][r][1] |= pb & 0xffff0000u;
        }
      }
    }
    #pragma unroll
    for (int qi = 0; qi < 4; ++qi)
      #pragma unroll
      for (int r = 0; r < 4; ++r)
        *(uint2*)&Pw[(qi * 16 + quad * 4 + r) * 68 + m16 * 4] =
            make_uint2(pk[qi][r][0], pk[qi][r][1]);
    // wave-private P region: RAW covered by lgkmcnt, no barrier

    // PV (32x32x16): accO[qs][dt], vb reused across qs
    #pragma unroll
    for (int ch = 0; ch < 4; ++ch) {
      bf16x8 pa0 = *(const bf16x8*)&Pw[m32 * 68 + ch * 16 + hl * 8];
      bf16x8 pa1 = *(const bf16x8*)&Pw[(32 + m32) * 68 + ch * 16 + hl * 8];
      bf16x8 vb0 = *(const bf16x8*)&Vs[m32 * 72 + ch * 16 + hl * 8];
      bf16x8 vb1 = *(const bf16x8*)&Vs[(32 + m32) * 72 + ch * 16 + hl * 8];
      accO[0][0] = __builtin_amdgcn_mfma_f32_32x32x16_bf16(pa0, vb0, accO[0][0], 0, 0, 0);
      accO[0][1] = __builtin_amdgcn_mfma_f32_32x32x16_bf16(pa0, vb1, accO[0][1], 0, 0, 0);
      accO[1][0] = __builtin_amdgcn_mfma_f32_32x32x16_bf16(pa1, vb0, accO[1][0], 0, 0, 0);
      accO[1][1] = __builtin_amdgcn_mfma_f32_32x32x16_bf16(pa1, vb1, accO[1][1], 0, 0, 0);
    }
  }

  // reduce row sums over the 16 n-lanes
  #pragma unroll
  for (int qi = 0; qi < 4; ++qi)
    #pragma unroll
    for (int r = 0; r < 4; ++r)
      #pragma unroll
      for (int off = 1; off < 16; off <<= 1)
        part[qi][r] += __shfl_xor(part[qi][r], off);

  // epilogue: per 32-row q-subtile, gather row sum, divide, store
  #pragma unroll
  for (int qs = 0; qs < 2; ++qs) {
    #pragma unroll
    for (int reg = 0; reg < 16; ++reg) {
      const int r = reg & 3;
      const int s = reg >> 2;
      const int qsrc = ((2 * s + hl) & 3) * 16 + m16;
      const float rs = __shfl(part[qs * 2 + (reg >> 3)][r], qsrc);
      const float inv = RCPF(rs);
      const int rho = r + 8 * s + 4 * hl;      // row in 32x32 C layout
      const size_t base = (size_t)(rowbase + qbase + qs * 32 + rho) * 2048 + h * 64;
      O[base + m32]      = f2bf(accO[qs][0][reg] * inv);
      O[base + 32 + m32] = f2bf(accO[qs][1][reg] * inv);
    }
  }
}

// ---------------------------------------------------------------------------
// launch
// ---------------------------------------------------------------------------
extern "C" void kernel_launch(void* const* d_in, const int* in_sizes, int n_in,
                              void* d_out, int out_size, void* d_ws, size_t ws_size,
                              hipStream_t stream) {
  (void)in_sizes; (void)n_in; (void)out_size; (void)ws_size;
  const float* x     = (const float*)d_in[0];
  const float* cond  = (const float*)d_in[1];
  const float* rope  = (const float*)d_in[2];
  const float* w_ada = (const float*)d_in[3];
  const float* w_qkv = (const float*)d_in[4];
  const float* w_out = (const float*)d_in[5];
  const float* qk_w  = (const float*)d_in[6];
  float* out = (float*)d_out;

  char* ws = (char*)d_ws;
  float*          ss   = (float*)ws;                       // 32 KB
  unsigned short* H    = (unsigned short*)(ws + 32768);    // 16 MB, reused as O
  unsigned short* Wq   = H + 8388608;                      // 24 MB
  unsigned short* Wo   = Wq + 12582912;                    // 8 MB  (contiguous after Wq)
  unsigned short* QKV  = Wo + 4194304;                     // 48 MB (q,k used)
  unsigned short* Vt_g = QKV + 25165824;                   // 16 MB

  ada_gemm_kernel<<<2048, 256, 0, stream>>>(cond, w_ada, ss);
  ada_rms_kernel<<<4096, 256, 0, stream>>>(x, ss, H);
  cast2_kernel<<<16384, 256, 0, stream>>>(w_qkv, w_out, Wq);
  // qkv = H @ w_qkv^T ; q,k -> QKV bf16, v -> Vt_g (transposed + k-permuted)
  gemm_qkv_8p<<<384, 512, 0, stream>>>(H, Wq, QKV, Vt_g);
  qk_rope_kernel<<<4096, 256, 0, stream>>>(QKV, rope, qk_w);
  attn_mfma_kernel<<<512, 256, 0, stream>>>(QKV, Vt_g, H);
  gemm_out_4p<<<256, 512, 0, stream>>>(H, Wo, out);
}